// Round 2
// baseline (2161.047 us; speedup 1.0000x reference)
//
#include <hip/hip_runtime.h>
#include <hip/hip_bf16.h>

// Problem constants
#define NN 20000
#define NE 100000
#define HID 256
#define HO 1024   // HEADS*OUT
#define HEADS 4
#define OUT 256

// ---------------------------------------------------------------------------
// K1: h = relu(x @ W_ne + b_ne)   x:[N,7] W:[7,256]
__global__ __launch_bounds__(256) void node_enc_kernel(
    const float* __restrict__ x, const float* __restrict__ W,
    const float* __restrict__ b, float* __restrict__ h)
{
    int n = blockIdx.x;
    int c = threadIdx.x;
    __shared__ float xs[8];
    if (threadIdx.x < 7) xs[threadIdx.x] = x[n * 7 + threadIdx.x];
    __syncthreads();
    float acc = b[c];
#pragma unroll
    for (int k = 0; k < 7; k++) acc += xs[k] * W[k * HID + c];
    h[n * HID + c] = fmaxf(acc, 0.f);
}

// ---------------------------------------------------------------------------
// Tiled f32 GEMM: C = A@B (+bias) or C += A@B (ACCUM). ldB for column blocks.
// BM=BN=64, BK=16, 256 threads, 4x4 per thread.
template <bool ACCUM>
__global__ __launch_bounds__(256) void gemm_kernel(
    const float* __restrict__ A, const float* __restrict__ B,
    const float* __restrict__ bias, float* __restrict__ C,
    int M, int N, int K, int ldB)
{
    constexpr int BM = 64, BN = 64, BK = 16;
    __shared__ float As[BK][BM];
    __shared__ float Bs[BK][BN];
    int tid = threadIdx.x;
    int tr = tid >> 4, tc = tid & 15;
    int rowBase = blockIdx.y * BM, colBase = blockIdx.x * BN;
    float acc[4][4] = {};
    for (int k0 = 0; k0 < K; k0 += BK) {
        {   // A tile load: thread -> one float4
            int r  = tid >> 2;
            int kk = (tid & 3) * 4;
            int row = rowBase + r;
            float4 v = make_float4(0.f, 0.f, 0.f, 0.f);
            if (row < M)
                v = *reinterpret_cast<const float4*>(&A[(size_t)row * K + k0 + kk]);
            As[kk + 0][r] = v.x; As[kk + 1][r] = v.y;
            As[kk + 2][r] = v.z; As[kk + 3][r] = v.w;
        }
        {   // B tile load
            int kk = tid >> 4;
            int n  = (tid & 15) * 4;
            float4 v = *reinterpret_cast<const float4*>(
                &B[(size_t)(k0 + kk) * ldB + colBase + n]);
            *reinterpret_cast<float4*>(&Bs[kk][n]) = v;
        }
        __syncthreads();
#pragma unroll
        for (int k = 0; k < BK; k++) {
            float4 a = *reinterpret_cast<const float4*>(&As[k][tr * 4]);
            float4 b = *reinterpret_cast<const float4*>(&Bs[k][tc * 4]);
            float av[4] = {a.x, a.y, a.z, a.w};
            float bv[4] = {b.x, b.y, b.z, b.w};
#pragma unroll
            for (int i = 0; i < 4; i++)
#pragma unroll
                for (int j = 0; j < 4; j++) acc[i][j] += av[i] * bv[j];
        }
        __syncthreads();
    }
#pragma unroll
    for (int i = 0; i < 4; i++) {
        int row = rowBase + tr * 4 + i;
        if (row >= M) continue;
#pragma unroll
        for (int j = 0; j < 4; j++) {
            int col = colBase + tc * 4 + j;
            size_t idx = (size_t)row * N + col;
            if constexpr (ACCUM) {
                C[idx] += acc[i][j];
            } else {
                C[idx] = acc[i][j] + bias[col];
            }
        }
    }
}

// ---------------------------------------------------------------------------
// K3 (per head): fused edge kernel. 16 edges/block, thread t = channel.
// e_enc (K=7) -> LDS; e_h column t accumulated in regs over k=0..255;
// z = lrelu(xl[s]+xr[d]+eh); logit = sum_c z*att; block-reduce;
// order-preserving-uint atomicMax for segment max.
constexpr int EPB = 16;

__global__ __launch_bounds__(256) void edge_logits_kernel(
    const float* __restrict__ edge_attr, const float* __restrict__ W_ee,
    const float* __restrict__ b_ee, const float* __restrict__ W_e,  // +h*256
    const float* __restrict__ b_e,  // +h*256
    const float* __restrict__ att,  // +h*256
    const float* __restrict__ xl, const float* __restrict__ xr,
    const int* __restrict__ ei, float* __restrict__ lbuf,
    unsigned int* __restrict__ mkey)
{
    __shared__ float eenc[EPB][HID];   // 16 KB
    __shared__ float red[EPB][4];
    int e0 = blockIdx.x * EPB;
    int t = threadIdx.x;

    float w[7];
#pragma unroll
    for (int k = 0; k < 7; k++) w[k] = W_ee[k * HID + t];
    float bee = b_ee[t];
    for (int i = 0; i < EPB; i++) {
        float acc = bee;
#pragma unroll
        for (int k = 0; k < 7; k++) acc += edge_attr[(size_t)(e0 + i) * 7 + k] * w[k];
        eenc[i][t] = fmaxf(acc, 0.f);
    }
    __syncthreads();

    float acc[EPB];
    float be = b_e[t];
#pragma unroll
    for (int i = 0; i < EPB; i++) acc[i] = be;

    for (int k = 0; k < HID; k += 4) {
        float4 wv;
        wv.x = W_e[(size_t)(k + 0) * HO + t];
        wv.y = W_e[(size_t)(k + 1) * HO + t];
        wv.z = W_e[(size_t)(k + 2) * HO + t];
        wv.w = W_e[(size_t)(k + 3) * HO + t];
#pragma unroll
        for (int i = 0; i < EPB; i++) {
            float4 s = *reinterpret_cast<const float4*>(&eenc[i][k]);
            acc[i] += s.x * wv.x + s.y * wv.y + s.z * wv.z + s.w * wv.w;
        }
    }

    float attv = att[t];
    int wave = t >> 6, lane = t & 63;
    for (int i = 0; i < EPB; i++) {
        int e = e0 + i;
        int s = ei[e], d = ei[NE + e];
        float z = xl[(size_t)s * HID + t] + xr[(size_t)d * HID + t] + acc[i];
        z = (z > 0.f) ? z : 0.2f * z;
        float v = z * attv;
#pragma unroll
        for (int off = 32; off; off >>= 1) v += __shfl_down(v, off);
        if (lane == 0) red[i][wave] = v;
    }
    __syncthreads();
    if (t < EPB) {
        int e = e0 + t;
        float v = red[t][0] + red[t][1] + red[t][2] + red[t][3];
        lbuf[e] = v;
        int d = ei[NE + e];
        unsigned int bits = __float_as_uint(v);
        unsigned int key = (bits & 0x80000000u) ? ~bits : (bits | 0x80000000u);
        atomicMax(&mkey[d], key);
    }
}

// ---------------------------------------------------------------------------
// K4 (per head): expv = exp(logit - m[dst]); denom[dst] += expv (in place)
__global__ __launch_bounds__(256) void expdenom_kernel(
    const unsigned int* __restrict__ mkey, const int* __restrict__ ei,
    float* __restrict__ lbuf, float* __restrict__ denom)
{
    int e = blockIdx.x * blockDim.x + threadIdx.x;
    if (e >= NE) return;
    int d = ei[NE + e];
    unsigned int key = mkey[d];
    unsigned int bits = (key & 0x80000000u) ? (key & 0x7FFFFFFFu) : ~key;
    float m = __uint_as_float(bits);
    float v = __expf(lbuf[e] - m);
    lbuf[e] = v;
    atomicAdd(&denom[d], v);
}

// ---------------------------------------------------------------------------
// K5 (per head): agg[dst] += (expv/denom[dst]) * xl[src]; one block per edge
__global__ __launch_bounds__(256) void aggregate_kernel(
    const float* __restrict__ expv, const float* __restrict__ denom,
    const int* __restrict__ ei, const float* __restrict__ xl,
    float* __restrict__ agg)
{
    int e = blockIdx.x;
    int t = threadIdx.x;
    int s = ei[e], d = ei[NE + e];
    float a = expv[e] / denom[d];
    atomicAdd(&agg[(size_t)d * HID + t], a * xl[(size_t)s * HID + t]);
}

// ---------------------------------------------------------------------------
// cb1[c] = sum_k conv_bias[k] * W_d1[k,c]   (one block, 256 threads)
__global__ __launch_bounds__(256) void cb1_kernel(
    const float* __restrict__ conv_bias, const float* __restrict__ W_d1,
    float* __restrict__ cb1)
{
    int c = threadIdx.x;
    float acc = 0.f;
    for (int k = 0; k < HO; k++) acc += conv_bias[k] * W_d1[(size_t)k * HID + c];
    cb1[c] = acc;
}

// hid = relu(hid_acc + b_d1 + cb1), in place
__global__ __launch_bounds__(256) void hid_relu_kernel(
    float* __restrict__ hid, const float* __restrict__ b_d1,
    const float* __restrict__ cb1)
{
    int g = blockIdx.x * blockDim.x + threadIdx.x;
    if (g >= NN * HID) return;
    int c = g & (HID - 1);
    hid[g] = fmaxf(hid[g] + b_d1[c] + cb1[c], 0.f);
}

// ---------------------------------------------------------------------------
// K7: out = sigmoid(hid @ W_d2 + b_d2)   hid:[N,256] W:[256,6]
__global__ __launch_bounds__(256) void final_kernel(
    const float* __restrict__ hid, const float* __restrict__ W_d2,
    const float* __restrict__ b_d2, float* __restrict__ out)
{
    int g = blockIdx.x * blockDim.x + threadIdx.x;
    if (g >= NN * 6) return;
    int n = g / 6, j = g % 6;
    float acc = b_d2[j];
    const float4* hp = reinterpret_cast<const float4*>(&hid[(size_t)n * HID]);
#pragma unroll 4
    for (int k4 = 0; k4 < HID / 4; k4++) {
        float4 hv = hp[k4];
        int k = k4 * 4;
        acc += hv.x * W_d2[(k + 0) * 6 + j] + hv.y * W_d2[(k + 1) * 6 + j] +
               hv.z * W_d2[(k + 2) * 6 + j] + hv.w * W_d2[(k + 3) * 6 + j];
    }
    out[g] = 1.f / (1.f + __expf(-acc));
}

// ---------------------------------------------------------------------------
extern "C" void kernel_launch(void* const* d_in, const int* in_sizes, int n_in,
                              void* d_out, int out_size, void* d_ws, size_t ws_size,
                              hipStream_t stream)
{
    const float* x         = (const float*)d_in[0];
    const float* edge_attr = (const float*)d_in[1];
    const float* W_ne = (const float*)d_in[2];  const float* b_ne = (const float*)d_in[3];
    const float* W_ee = (const float*)d_in[4];  const float* b_ee = (const float*)d_in[5];
    const float* W_l  = (const float*)d_in[6];  const float* b_l  = (const float*)d_in[7];
    const float* W_r  = (const float*)d_in[8];  const float* b_r  = (const float*)d_in[9];
    const float* W_e  = (const float*)d_in[10]; const float* b_e  = (const float*)d_in[11];
    const float* att  = (const float*)d_in[12];
    const float* conv_bias = (const float*)d_in[13];
    const float* W_d1 = (const float*)d_in[14]; const float* b_d1 = (const float*)d_in[15];
    const float* W_d2 = (const float*)d_in[16]; const float* b_d2 = (const float*)d_in[17];
    const int*   ei   = (const int*)d_in[18];
    float* out = (float*)d_out;

    // compact per-head workspace layout (f32 elements)
    const size_t NODE = (size_t)NN * HID;        // 5.12M
    float* h       = (float*)d_ws;               // [NODE]
    float* xl      = h      + NODE;              // [NODE]
    float* xr_agg  = xl     + NODE;              // [NODE]  xr, then agg (aliased)
    float* hid_acc = xr_agg + NODE;              // [NODE]
    float* lbuf    = hid_acc + NODE;             // [NE]
    float* denom   = lbuf   + NE;                // [NN]
    unsigned int* mkey = (unsigned int*)(denom + NN); // [NN]
    float* cb1     = (float*)mkey + NN;          // [HID]

    size_t need = ((size_t)4 * NODE + NE + 2 * NN + HID) * 4;
    if (ws_size < need) return;  // clean fail instead of OOB abort

    // node encoder + decoder bias precompute + zero hid accumulator
    hipMemsetAsync(hid_acc, 0, NODE * 4, stream);
    node_enc_kernel<<<NN, 256, 0, stream>>>(x, W_ne, b_ne, h);
    cb1_kernel<<<1, 256, 0, stream>>>(conv_bias, W_d1, cb1);

    dim3 gemmGrid(HID / 64, (NN + 63) / 64);

    for (int hh = 0; hh < HEADS; hh++) {
        const float* Wl_b = W_l + hh * OUT;              // cols block, ldB=HO
        const float* Wr_b = W_r + hh * OUT;
        const float* We_b = W_e + hh * OUT;
        const float* Wd1_b = W_d1 + (size_t)hh * OUT * HID;  // rows block, ldB=HID

        // xl_h, xr_h  [NN,256]
        gemm_kernel<false><<<gemmGrid, 256, 0, stream>>>(
            h, Wl_b, b_l + hh * OUT, xl, NN, HID, HID, HO);
        gemm_kernel<false><<<gemmGrid, 256, 0, stream>>>(
            h, Wr_b, b_r + hh * OUT, xr_agg, NN, HID, HID, HO);

        hipMemsetAsync(mkey,  0, (size_t)NN * 4, stream);
        hipMemsetAsync(denom, 0, (size_t)NN * 4, stream);

        // fused edge encoder + e_h + logits + segment max
        edge_logits_kernel<<<NE / EPB, 256, 0, stream>>>(
            edge_attr, W_ee, b_ee, We_b, b_e + hh * OUT, att + hh * OUT,
            xl, xr_agg, ei, lbuf, mkey);

        // exp + denominators
        expdenom_kernel<<<(NE + 255) / 256, 256, 0, stream>>>(mkey, ei, lbuf, denom);

        // xr dead -> reuse as agg
        hipMemsetAsync(xr_agg, 0, NODE * 4, stream);
        aggregate_kernel<<<NE, 256, 0, stream>>>(lbuf, denom, ei, xl, xr_agg);

        // hid_acc += agg_h @ W_d1[h*256:(h+1)*256, :]
        gemm_kernel<true><<<gemmGrid, 256, 0, stream>>>(
            xr_agg, Wd1_b, nullptr, hid_acc, NN, HID, HID, HID);
    }

    // decoder layer-1 activation, then layer-2 + sigmoid
    hid_relu_kernel<<<(NN * HID + 255) / 256, 256, 0, stream>>>(hid_acc, b_d1, cb1);
    final_kernel<<<(NN * 6 + 255) / 256, 256, 0, stream>>>(hid_acc, W_d2, b_d2, out);
}

// Round 3
// 1125.769 us; speedup vs baseline: 1.9196x; 1.9196x over previous
//
#include <hip/hip_runtime.h>
#include <hip/hip_bf16.h>

#define NN 20000
#define NE 100000
#define HID 256
#define HO 1024   // HEADS*OUT
#define HEADS 4
#define OUT 256

typedef __attribute__((ext_vector_type(8))) short bf16x8;
typedef __attribute__((ext_vector_type(4))) float f32x4;

__device__ inline ushort f2bf(float f) {
    union { float f; unsigned u; } v; v.f = f;
    unsigned r = v.u + 0x7FFFu + ((v.u >> 16) & 1u);  // RNE
    return (ushort)(r >> 16);
}
__device__ inline float bf2f(ushort b) {
    union { unsigned u; float f; } v; v.u = ((unsigned)b) << 16;
    return v.f;
}

// ---------------------------------------------------------------------------
// K1: h_bf = bf16(relu(x @ W_ne + b_ne))   x:[N,7] W:[7,256]
__global__ __launch_bounds__(256) void node_enc_kernel(
    const float* __restrict__ x, const float* __restrict__ W,
    const float* __restrict__ b, ushort* __restrict__ h)
{
    int n = blockIdx.x;
    int c = threadIdx.x;
    __shared__ float xs[8];
    if (threadIdx.x < 7) xs[threadIdx.x] = x[n * 7 + threadIdx.x];
    __syncthreads();
    float acc = b[c];
#pragma unroll
    for (int k = 0; k < 7; k++) acc += xs[k] * W[k * HID + c];
    h[(size_t)n * HID + c] = f2bf(fmaxf(acc, 0.f));
}

// ---------------------------------------------------------------------------
// WT[n][k] = bf16(W[(row0+k)*ldW + colOff + n])   grid=256 (k), 256 thr (n)
__global__ __launch_bounds__(256) void transpose_bf16_kernel(
    const float* __restrict__ W, ushort* __restrict__ WT,
    int ldW, int row0, int colOff)
{
    int k = blockIdx.x;
    int n = threadIdx.x;
    WT[(size_t)n * 256 + k] = f2bf(W[(size_t)(row0 + k) * ldW + colOff + n]);
}

// ---------------------------------------------------------------------------
// MFMA GEMM: C = A[M,256] @ BT[256,256]^T   (BT is [n][k], bf16)
// OUT_BF16: C bf16 with +bias.  else: C f32 += (accumulate).
// Block: 256 thr (4 waves), tile 64 rows x 256 cols; wave w -> cols [w*64,w*64+64)
template <bool OUT_BF16>
__global__ __launch_bounds__(256) void mfma_gemm_kernel(
    const ushort* __restrict__ A, const ushort* __restrict__ BT,
    const float* __restrict__ bias, void* __restrict__ Cv, int M)
{
    int t = threadIdx.x, w = t >> 6, lane = t & 63;
    int l15 = lane & 15, l4 = lane >> 4;
    int row0 = blockIdx.x * 64;
    f32x4 acc[4][4] = {};
    for (int k0 = 0; k0 < 256; k0 += 32) {
        bf16x8 a[4], b[4];
#pragma unroll
        for (int rt = 0; rt < 4; rt++) {
            int row = row0 + rt * 16 + l15;
            if (row < M) a[rt] = *(const bf16x8*)&A[(size_t)row * 256 + k0 + l4 * 8];
            else         a[rt] = (bf16x8){0, 0, 0, 0, 0, 0, 0, 0};
        }
#pragma unroll
        for (int ct = 0; ct < 4; ct++) {
            int n = w * 64 + ct * 16 + l15;
            b[ct] = *(const bf16x8*)&BT[(size_t)n * 256 + k0 + l4 * 8];
        }
#pragma unroll
        for (int rt = 0; rt < 4; rt++)
#pragma unroll
            for (int ct = 0; ct < 4; ct++)
                acc[rt][ct] = __builtin_amdgcn_mfma_f32_16x16x32_bf16(
                    a[rt], b[ct], acc[rt][ct], 0, 0, 0);
    }
    if constexpr (OUT_BF16) {
        ushort* C = (ushort*)Cv;
        float bv[4];
#pragma unroll
        for (int ct = 0; ct < 4; ct++) bv[ct] = bias[w * 64 + ct * 16 + l15];
#pragma unroll
        for (int rt = 0; rt < 4; rt++)
#pragma unroll
            for (int ct = 0; ct < 4; ct++)
#pragma unroll
                for (int r = 0; r < 4; r++) {
                    int row = row0 + rt * 16 + l4 * 4 + r;
                    if (row < M)
                        C[(size_t)row * 256 + w * 64 + ct * 16 + l15] =
                            f2bf(acc[rt][ct][r] + bv[ct]);
                }
    } else {
        float* C = (float*)Cv;
#pragma unroll
        for (int rt = 0; rt < 4; rt++)
#pragma unroll
            for (int ct = 0; ct < 4; ct++)
#pragma unroll
                for (int r = 0; r < 4; r++) {
                    int row = row0 + rt * 16 + l4 * 4 + r;
                    if (row < M)
                        C[(size_t)row * 256 + w * 64 + ct * 16 + l15] += acc[rt][ct][r];
                }
    }
}

// ---------------------------------------------------------------------------
// Fused edge kernel (per head): 32 edges/block.
// Phase 1: e_enc tile [32,256] bf16 -> LDS (recomputed, K=7).
// Phase 2: e_h tile via MFMA vs W_e^T head slice.
// Phase 3: z = lrelu(e_h + b_e + xl[src] + xr[dst]); logit = sum_c z*att;
//          16-lane shfl reduce + cross-wave LDS reduce; atomicMax seg-max.
__global__ __launch_bounds__(256) void edge_mfma_logits_kernel(
    const float* __restrict__ edge_attr, const float* __restrict__ W_ee,
    const float* __restrict__ b_ee, const ushort* __restrict__ WeT,
    const float* __restrict__ b_e_h, const float* __restrict__ att_h,
    const ushort* __restrict__ xl, const ushort* __restrict__ xr,
    const int* __restrict__ ei, float* __restrict__ lbuf,
    unsigned int* __restrict__ mkey)
{
    __shared__ ushort As[32][264];   // padded: 264*2=528B rows -> 2-way max
    __shared__ float ea[224];        // 32 edges x 7 attrs
    __shared__ float red[4][32];
    int e0 = blockIdx.x * 32;
    int t = threadIdx.x, w = t >> 6, lane = t & 63;
    int l15 = lane & 15, l4 = lane >> 4;

    if (t < 224) ea[t] = edge_attr[(size_t)e0 * 7 + t];
    float w7[7];
#pragma unroll
    for (int k = 0; k < 7; k++) w7[k] = W_ee[k * HID + t];
    float bee = b_ee[t];
    __syncthreads();
#pragma unroll 4
    for (int r = 0; r < 32; r++) {
        float acc = bee;
#pragma unroll
        for (int k = 0; k < 7; k++) acc += w7[k] * ea[r * 7 + k];
        As[r][t] = f2bf(fmaxf(acc, 0.f));
    }
    __syncthreads();

    f32x4 acc[2][4] = {};
    for (int k0 = 0; k0 < 256; k0 += 32) {
        bf16x8 a[2], b[4];
#pragma unroll
        for (int rt = 0; rt < 2; rt++)
            a[rt] = *(const bf16x8*)&As[rt * 16 + l15][k0 + l4 * 8];
#pragma unroll
        for (int ct = 0; ct < 4; ct++) {
            int n = w * 64 + ct * 16 + l15;
            b[ct] = *(const bf16x8*)&WeT[(size_t)n * 256 + k0 + l4 * 8];
        }
#pragma unroll
        for (int rt = 0; rt < 2; rt++)
#pragma unroll
            for (int ct = 0; ct < 4; ct++)
                acc[rt][ct] = __builtin_amdgcn_mfma_f32_16x16x32_bf16(
                    a[rt], b[ct], acc[rt][ct], 0, 0, 0);
    }

    float bev[4], atv[4];
#pragma unroll
    for (int ct = 0; ct < 4; ct++) {
        int col = w * 64 + ct * 16 + l15;
        bev[ct] = b_e_h[col];
        atv[ct] = att_h[col];
    }

    float lp[2][4];
#pragma unroll
    for (int rt = 0; rt < 2; rt++)
#pragma unroll
        for (int r = 0; r < 4; r++) {
            int e = e0 + rt * 16 + l4 * 4 + r;
            int s = ei[e], d = ei[NE + e];
            float p = 0.f;
#pragma unroll
            for (int ct = 0; ct < 4; ct++) {
                int col = w * 64 + ct * 16 + l15;
                float z = acc[rt][ct][r] + bev[ct] +
                          bf2f(xl[(size_t)s * 256 + col]) +
                          bf2f(xr[(size_t)d * 256 + col]);
                z = (z > 0.f) ? z : 0.2f * z;
                p += z * atv[ct];
            }
            lp[rt][r] = p;
        }
#pragma unroll
    for (int off = 1; off < 16; off <<= 1) {
#pragma unroll
        for (int rt = 0; rt < 2; rt++)
#pragma unroll
            for (int r = 0; r < 4; r++)
                lp[rt][r] += __shfl_xor(lp[rt][r], off);
    }
    if (l15 == 0) {
#pragma unroll
        for (int rt = 0; rt < 2; rt++)
#pragma unroll
            for (int r = 0; r < 4; r++)
                red[w][rt * 16 + l4 * 4 + r] = lp[rt][r];
    }
    __syncthreads();
    if (t < 32) {
        float v = red[0][t] + red[1][t] + red[2][t] + red[3][t];
        int e = e0 + t;
        lbuf[e] = v;
        int d = ei[NE + e];
        unsigned int bits = __float_as_uint(v);
        unsigned int key = (bits & 0x80000000u) ? ~bits : (bits | 0x80000000u);
        atomicMax(&mkey[d], key);
    }
}

// ---------------------------------------------------------------------------
// expv = exp(logit - m[dst]); denom[dst] += expv  (in place on lbuf)
__global__ __launch_bounds__(256) void expdenom_kernel(
    const unsigned int* __restrict__ mkey, const int* __restrict__ ei,
    float* __restrict__ lbuf, float* __restrict__ denom)
{
    int e = blockIdx.x * blockDim.x + threadIdx.x;
    if (e >= NE) return;
    int d = ei[NE + e];
    unsigned int key = mkey[d];
    unsigned int bits = (key & 0x80000000u) ? (key & 0x7FFFFFFFu) : ~key;
    float m = __uint_as_float(bits);
    float v = __expf(lbuf[e] - m);
    lbuf[e] = v;
    atomicAdd(&denom[d], v);
}

// ---------------------------------------------------------------------------
// agg[dst] += (expv/denom[dst]) * xl[src]; one block per edge
__global__ __launch_bounds__(256) void aggregate_kernel(
    const float* __restrict__ expv, const float* __restrict__ denom,
    const int* __restrict__ ei, const ushort* __restrict__ xl,
    float* __restrict__ agg)
{
    int e = blockIdx.x;
    int t = threadIdx.x;
    int s = ei[e], d = ei[NE + e];
    float a = expv[e] / denom[d];
    atomicAdd(&agg[(size_t)d * HID + t], a * bf2f(xl[(size_t)s * HID + t]));
}

// ---------------------------------------------------------------------------
__global__ __launch_bounds__(256) void f32_to_bf16_kernel(
    const float* __restrict__ in, ushort* __restrict__ o, int n4)
{
    int g = blockIdx.x * blockDim.x + threadIdx.x;
    if (g >= n4) return;
    float4 v = ((const float4*)in)[g];
    ushort4 u;
    u.x = f2bf(v.x); u.y = f2bf(v.y); u.z = f2bf(v.z); u.w = f2bf(v.w);
    ((ushort4*)o)[g] = u;
}

// ---------------------------------------------------------------------------
// cb1[c] = sum_k conv_bias[k] * W_d1[k,c]
__global__ __launch_bounds__(256) void cb1_kernel(
    const float* __restrict__ conv_bias, const float* __restrict__ W_d1,
    float* __restrict__ cb1)
{
    int c = threadIdx.x;
    float acc = 0.f;
    for (int k = 0; k < HO; k++) acc += conv_bias[k] * W_d1[(size_t)k * HID + c];
    cb1[c] = acc;
}

// hid = relu(hid_acc + b_d1 + cb1), in place
__global__ __launch_bounds__(256) void hid_relu_kernel(
    float* __restrict__ hid, const float* __restrict__ b_d1,
    const float* __restrict__ cb1)
{
    int g = blockIdx.x * blockDim.x + threadIdx.x;
    if (g >= NN * HID) return;
    int c = g & (HID - 1);
    hid[g] = fmaxf(hid[g] + b_d1[c] + cb1[c], 0.f);
}

// ---------------------------------------------------------------------------
// out = sigmoid(hid @ W_d2 + b_d2)   hid:[N,256] W:[256,6]
__global__ __launch_bounds__(256) void final_kernel(
    const float* __restrict__ hid, const float* __restrict__ W_d2,
    const float* __restrict__ b_d2, float* __restrict__ out)
{
    int g = blockIdx.x * blockDim.x + threadIdx.x;
    if (g >= NN * 6) return;
    int n = g / 6, j = g % 6;
    float acc = b_d2[j];
    const float4* hp = reinterpret_cast<const float4*>(&hid[(size_t)n * HID]);
#pragma unroll 4
    for (int k4 = 0; k4 < HID / 4; k4++) {
        float4 hv = hp[k4];
        int k = k4 * 4;
        acc += hv.x * W_d2[(k + 0) * 6 + j] + hv.y * W_d2[(k + 1) * 6 + j] +
               hv.z * W_d2[(k + 2) * 6 + j] + hv.w * W_d2[(k + 3) * 6 + j];
    }
    out[g] = 1.f / (1.f + __expf(-acc));
}

// ---------------------------------------------------------------------------
extern "C" void kernel_launch(void* const* d_in, const int* in_sizes, int n_in,
                              void* d_out, int out_size, void* d_ws, size_t ws_size,
                              hipStream_t stream)
{
    const float* x         = (const float*)d_in[0];
    const float* edge_attr = (const float*)d_in[1];
    const float* W_ne = (const float*)d_in[2];  const float* b_ne = (const float*)d_in[3];
    const float* W_ee = (const float*)d_in[4];  const float* b_ee = (const float*)d_in[5];
    const float* W_l  = (const float*)d_in[6];  const float* b_l  = (const float*)d_in[7];
    const float* W_r  = (const float*)d_in[8];  const float* b_r  = (const float*)d_in[9];
    const float* W_e  = (const float*)d_in[10]; const float* b_e  = (const float*)d_in[11];
    const float* att  = (const float*)d_in[12];
    const float* conv_bias = (const float*)d_in[13];
    const float* W_d1 = (const float*)d_in[14]; const float* b_d1 = (const float*)d_in[15];
    const float* W_d2 = (const float*)d_in[16]; const float* b_d2 = (const float*)d_in[17];
    const int*   ei   = (const int*)d_in[18];
    float* out = (float*)d_out;

    // workspace layout (bytes)
    const size_t NODEH = (size_t)NN * HID;   // 5.12M elems
    char* p = (char*)d_ws;
    ushort* h_bf   = (ushort*)p;            p += NODEH * 2;        // 10.24 MB
    ushort* xl_bf  = (ushort*)p;            p += NODEH * 2;
    ushort* xr_bf  = (ushort*)p;            p += NODEH * 2;
    ushort* agg_bf = (ushort*)p;            p += NODEH * 2;
    float*  agg    = (float*)p;             p += NODEH * 4;        // 20.48 MB
    float*  hid    = (float*)p;             p += NODEH * 4;
    float*  lbuf   = (float*)p;             p += (size_t)NE * 4;
    float*  denom  = (float*)p;             p += (size_t)NN * 4;
    unsigned int* mkey = (unsigned int*)p;  p += (size_t)NN * 4;
    float*  cb1    = (float*)p;             p += HID * 4;
    ushort* WlT    = (ushort*)p;            p += 65536 * 2;        // 128 KB each
    ushort* WrT    = (ushort*)p;            p += 65536 * 2;
    ushort* WeT    = (ushort*)p;            p += 65536 * 2;
    ushort* Wd1T   = (ushort*)p;            p += 65536 * 2;
    if ((size_t)(p - (char*)d_ws) > ws_size) return;  // clean fail, no OOB

    hipMemsetAsync(hid, 0, NODEH * 4, stream);
    node_enc_kernel<<<NN, 256, 0, stream>>>(x, W_ne, b_ne, h_bf);
    cb1_kernel<<<1, 256, 0, stream>>>(conv_bias, W_d1, cb1);

    const int gemmGrid = (NN + 63) / 64;   // 313

    for (int hh = 0; hh < HEADS; hh++) {
        // per-head transposed bf16 weights
        transpose_bf16_kernel<<<256, 256, 0, stream>>>(W_l,  WlT,  HO,  0, hh * OUT);
        transpose_bf16_kernel<<<256, 256, 0, stream>>>(W_r,  WrT,  HO,  0, hh * OUT);
        transpose_bf16_kernel<<<256, 256, 0, stream>>>(W_e,  WeT,  HO,  0, hh * OUT);
        transpose_bf16_kernel<<<256, 256, 0, stream>>>(W_d1, Wd1T, HID, hh * OUT, 0);

        // xl, xr  [NN,256] bf16
        mfma_gemm_kernel<true><<<gemmGrid, 256, 0, stream>>>(
            h_bf, WlT, b_l + hh * OUT, xl_bf, NN);
        mfma_gemm_kernel<true><<<gemmGrid, 256, 0, stream>>>(
            h_bf, WrT, b_r + hh * OUT, xr_bf, NN);

        hipMemsetAsync(mkey,  0, (size_t)NN * 4, stream);
        hipMemsetAsync(denom, 0, (size_t)NN * 4, stream);

        edge_mfma_logits_kernel<<<NE / 32, 256, 0, stream>>>(
            edge_attr, W_ee, b_ee, WeT, b_e + hh * OUT, att + hh * OUT,
            xl_bf, xr_bf, ei, lbuf, mkey);

        expdenom_kernel<<<(NE + 255) / 256, 256, 0, stream>>>(mkey, ei, lbuf, denom);

        hipMemsetAsync(agg, 0, NODEH * 4, stream);
        aggregate_kernel<<<NE, 256, 0, stream>>>(lbuf, denom, ei, xl_bf, agg);

        // hid += agg @ W_d1[h*256:(h+1)*256, :]
        f32_to_bf16_kernel<<<(int)(NODEH / 4 + 255) / 256, 256, 0, stream>>>(
            agg, agg_bf, (int)(NODEH / 4));
        mfma_gemm_kernel<false><<<gemmGrid, 256, 0, stream>>>(
            agg_bf, Wd1T, nullptr, hid, NN);
    }

    hid_relu_kernel<<<(NN * HID + 255) / 256, 256, 0, stream>>>(hid, b_d1, cb1);
    final_kernel<<<(NN * 6 + 255) / 256, 256, 0, stream>>>(hid, W_d2, b_d2, out);
}

// Round 4
// 1052.260 us; speedup vs baseline: 2.0537x; 1.0699x over previous
//
#include <hip/hip_runtime.h>
#include <hip/hip_bf16.h>

#define NN 20000
#define NE 100000
#define HID 256
#define HO 1024   // HEADS*OUT
#define HEADS 4
#define OUT 256

typedef __attribute__((ext_vector_type(8))) short bf16x8;
typedef __attribute__((ext_vector_type(4))) float f32x4;

__device__ inline ushort f2bf(float f) {
    union { float f; unsigned u; } v; v.f = f;
    unsigned r = v.u + 0x7FFFu + ((v.u >> 16) & 1u);  // RNE
    return (ushort)(r >> 16);
}
__device__ inline float bf2f(ushort b) {
    union { unsigned u; float f; } v; v.u = ((unsigned)b) << 16;
    return v.f;
}

// ---------------------------------------------------------------------------
// K1: h_bf = bf16(relu(x @ W_ne + b_ne))   x:[N,7] W:[7,256]
__global__ __launch_bounds__(256) void node_enc_kernel(
    const float* __restrict__ x, const float* __restrict__ W,
    const float* __restrict__ b, ushort* __restrict__ h)
{
    int n = blockIdx.x;
    int c = threadIdx.x;
    __shared__ float xs[8];
    if (threadIdx.x < 7) xs[threadIdx.x] = x[n * 7 + threadIdx.x];
    __syncthreads();
    float acc = b[c];
#pragma unroll
    for (int k = 0; k < 7; k++) acc += xs[k] * W[k * HID + c];
    h[(size_t)n * HID + c] = f2bf(fmaxf(acc, 0.f));
}

// ---------------------------------------------------------------------------
// WT[n][k] = bf16(W[k][n])   W:[K,N]  grid=dim3(K, N/256)
__global__ __launch_bounds__(256) void transpose_bf16_kernel(
    const float* __restrict__ W, ushort* __restrict__ WT, int K, int N)
{
    int k = blockIdx.x;
    int n = blockIdx.y * 256 + threadIdx.x;
    WT[(size_t)n * K + k] = f2bf(W[(size_t)k * N + n]);
}

// ---------------------------------------------------------------------------
// biasH[c] = b_d1[c] + sum_k conv_bias[k] * W_d1[k,c]
__global__ __launch_bounds__(256) void biasH_kernel(
    const float* __restrict__ conv_bias, const float* __restrict__ W_d1,
    const float* __restrict__ b_d1, float* __restrict__ biasH)
{
    int c = threadIdx.x;
    float acc = b_d1[c];
    for (int k = 0; k < HO; k++) acc += conv_bias[k] * W_d1[(size_t)k * HID + c];
    biasH[c] = acc;
}

// ---------------------------------------------------------------------------
// CSR build
__global__ __launch_bounds__(256) void hist_kernel(
    const int* __restrict__ ei, int* __restrict__ deg)
{
    int e = blockIdx.x * blockDim.x + threadIdx.x;
    if (e >= NE) return;
    atomicAdd(&deg[ei[NE + e]], 1);
}

__global__ __launch_bounds__(64) void scan_kernel(
    const int* __restrict__ deg, int* __restrict__ rowptr, int* __restrict__ cursor)
{
    const int CH = 313;   // 64*313 = 20032 >= 20000
    int t = threadIdx.x;
    int start = t * CH, end = min(NN, start + CH);
    int local = 0;
    for (int i = start; i < end; i++) local += deg[i];
    int incl = local;
#pragma unroll
    for (int off = 1; off < 64; off <<= 1) {
        int v = __shfl_up(incl, off);
        if (t >= off) incl += v;
    }
    int run = incl - local;
    for (int i = start; i < end; i++) {
        rowptr[i] = run;
        cursor[i] = run;
        run += deg[i];
    }
    if (t == 63) rowptr[NN] = run;
}

__global__ __launch_bounds__(256) void scatter_kernel(
    const int* __restrict__ ei, int* __restrict__ cursor, int* __restrict__ eidx)
{
    int e = blockIdx.x * blockDim.x + threadIdx.x;
    if (e >= NE) return;
    int d = ei[NE + e];
    int pos = atomicAdd(&cursor[d], 1);
    eidx[pos] = e;
}

// ---------------------------------------------------------------------------
// MFMA GEMM: C[M,256] = A[M,K] @ BT[256,K]^T   (BT row n = column n of B)
// MODE 0: C bf16 = result + bias.  MODE 1: C f32 += result.
template <int MODE>
__global__ __launch_bounds__(256) void mfma_gemm_kernel(
    const ushort* __restrict__ A, const ushort* __restrict__ BT, int ldBT, int K,
    const float* __restrict__ bias, void* __restrict__ Cv, int M)
{
    int t = threadIdx.x, w = t >> 6, lane = t & 63;
    int l15 = lane & 15, l4 = lane >> 4;
    int row0 = blockIdx.x * 64;
    f32x4 acc[4][4] = {};
    for (int k0 = 0; k0 < K; k0 += 32) {
        bf16x8 a[4], b[4];
#pragma unroll
        for (int rt = 0; rt < 4; rt++) {
            int row = row0 + rt * 16 + l15;
            if (row < M) a[rt] = *(const bf16x8*)&A[(size_t)row * K + k0 + l4 * 8];
            else         a[rt] = (bf16x8){0, 0, 0, 0, 0, 0, 0, 0};
        }
#pragma unroll
        for (int ct = 0; ct < 4; ct++) {
            int n = w * 64 + ct * 16 + l15;
            b[ct] = *(const bf16x8*)&BT[(size_t)n * ldBT + k0 + l4 * 8];
        }
#pragma unroll
        for (int rt = 0; rt < 4; rt++)
#pragma unroll
            for (int ct = 0; ct < 4; ct++)
                acc[rt][ct] = __builtin_amdgcn_mfma_f32_16x16x32_bf16(
                    a[rt], b[ct], acc[rt][ct], 0, 0, 0);
    }
    if constexpr (MODE == 0) {
        ushort* C = (ushort*)Cv;
        float bv[4];
#pragma unroll
        for (int ct = 0; ct < 4; ct++) bv[ct] = bias[w * 64 + ct * 16 + l15];
#pragma unroll
        for (int rt = 0; rt < 4; rt++)
#pragma unroll
            for (int ct = 0; ct < 4; ct++)
#pragma unroll
                for (int r = 0; r < 4; r++) {
                    int row = row0 + rt * 16 + l4 * 4 + r;
                    if (row < M)
                        C[(size_t)row * 256 + w * 64 + ct * 16 + l15] =
                            f2bf(acc[rt][ct][r] + bv[ct]);
                }
    } else {
        float* C = (float*)Cv;
#pragma unroll
        for (int rt = 0; rt < 4; rt++)
#pragma unroll
            for (int ct = 0; ct < 4; ct++)
#pragma unroll
                for (int r = 0; r < 4; r++) {
                    int row = row0 + rt * 16 + l4 * 4 + r;
                    if (row < M)
                        C[(size_t)row * 256 + w * 64 + ct * 16 + l15] += acc[rt][ct][r];
                }
    }
}

// ---------------------------------------------------------------------------
// Fused edge kernel (per head): 64 edges/block.
// e_enc [64,256] bf16 -> LDS (K=7 recompute); e_h via MFMA vs WeT head slice;
// logit = sum_c lrelu(e_h + b_e + xl[s] + xr[d]) * att; write lbuf4[e*4+h].
__global__ __launch_bounds__(256) void edge_mfma_logits_kernel(
    const float* __restrict__ edge_attr, const float* __restrict__ W_ee,
    const float* __restrict__ b_ee, const ushort* __restrict__ WeTh,
    const float* __restrict__ b_e_h, const float* __restrict__ att_h,
    const ushort* __restrict__ xl, const ushort* __restrict__ xr,
    const int* __restrict__ ei, float* __restrict__ lbuf4, int h)
{
    __shared__ ushort As[64][264];   // padded rows (528 B)
    __shared__ float ea[448];        // 64 edges x 7 attrs
    __shared__ int sArr[64], dArr[64];
    __shared__ float red[4][64];
    int e0 = blockIdx.x * 64;
    int t = threadIdx.x, w = t >> 6, lane = t & 63;
    int l15 = lane & 15, l4 = lane >> 4;
    int nval = NE - e0; if (nval > 64) nval = 64;

    for (int i = t; i < 448; i += 256)
        ea[i] = (i < nval * 7) ? edge_attr[(size_t)e0 * 7 + i] : 0.f;
    if (t < 64) {
        int e = e0 + t;
        sArr[t] = (t < nval) ? ei[e] : 0;
        dArr[t] = (t < nval) ? ei[NE + e] : 0;
    }
    float w7[7];
#pragma unroll
    for (int k = 0; k < 7; k++) w7[k] = W_ee[k * HID + t];
    float bee = b_ee[t];
    __syncthreads();
#pragma unroll 4
    for (int r = 0; r < 64; r++) {
        float acc = bee;
#pragma unroll
        for (int k = 0; k < 7; k++) acc += w7[k] * ea[r * 7 + k];
        As[r][t] = f2bf(fmaxf(acc, 0.f));
    }
    __syncthreads();

    f32x4 acc[4][4] = {};
    for (int k0 = 0; k0 < 256; k0 += 32) {
        bf16x8 a[4], b[4];
#pragma unroll
        for (int rt = 0; rt < 4; rt++)
            a[rt] = *(const bf16x8*)&As[rt * 16 + l15][k0 + l4 * 8];
#pragma unroll
        for (int ct = 0; ct < 4; ct++) {
            int n = w * 64 + ct * 16 + l15;
            b[ct] = *(const bf16x8*)&WeTh[(size_t)n * 256 + k0 + l4 * 8];
        }
#pragma unroll
        for (int rt = 0; rt < 4; rt++)
#pragma unroll
            for (int ct = 0; ct < 4; ct++)
                acc[rt][ct] = __builtin_amdgcn_mfma_f32_16x16x32_bf16(
                    a[rt], b[ct], acc[rt][ct], 0, 0, 0);
    }

    float bev[4], atv[4];
#pragma unroll
    for (int ct = 0; ct < 4; ct++) {
        int col = w * 64 + ct * 16 + l15;
        bev[ct] = b_e_h[col];
        atv[ct] = att_h[col];
    }

    float lp[4][4];
#pragma unroll
    for (int rt = 0; rt < 4; rt++)
#pragma unroll
        for (int r = 0; r < 4; r++) {
            int idx = rt * 16 + l4 * 4 + r;
            int s = sArr[idx], d = dArr[idx];
            float p = 0.f;
#pragma unroll
            for (int ct = 0; ct < 4; ct++) {
                int col = w * 64 + ct * 16 + l15;
                float z = acc[rt][ct][r] + bev[ct] +
                          bf2f(xl[(size_t)s * 256 + col]) +
                          bf2f(xr[(size_t)d * 256 + col]);
                z = (z > 0.f) ? z : 0.2f * z;
                p += z * atv[ct];
            }
            lp[rt][r] = p;
        }
#pragma unroll
    for (int off = 1; off < 16; off <<= 1)
#pragma unroll
        for (int rt = 0; rt < 4; rt++)
#pragma unroll
            for (int r = 0; r < 4; r++)
                lp[rt][r] += __shfl_xor(lp[rt][r], off);
    if (l15 == 0)
#pragma unroll
        for (int rt = 0; rt < 4; rt++)
#pragma unroll
            for (int r = 0; r < 4; r++)
                red[w][rt * 16 + l4 * 4 + r] = lp[rt][r];
    __syncthreads();
    if (t < nval) {
        float v = red[0][t] + red[1][t] + red[2][t] + red[3][t];
        lbuf4[(size_t)(e0 + t) * 4 + h] = v;
    }
}

// ---------------------------------------------------------------------------
// Fused segment softmax + aggregation (per head). One wave per dst node.
// agg_bf[n][c] = sum_j alpha_j * xl[src_j][c], alpha via stable softmax.
__global__ __launch_bounds__(256) void softmax_agg_kernel(
    const float* __restrict__ lbuf4, const int* __restrict__ rowptr,
    const int* __restrict__ eidx, const int* __restrict__ ei,
    const ushort* __restrict__ xl, ushort* __restrict__ agg, int h)
{
    int wv = threadIdx.x >> 6, lane = threadIdx.x & 63;
    int n = blockIdx.x * 4 + wv;
    if (n >= NN) return;
    int r0 = rowptr[n], r1 = rowptr[n + 1];
    float m = -3.4e38f;
    for (int j = r0; j < r1; j++)
        m = fmaxf(m, lbuf4[(size_t)eidx[j] * 4 + h]);
    float denom = 0.f;
    for (int j = r0; j < r1; j++)
        denom += __expf(lbuf4[(size_t)eidx[j] * 4 + h] - m);
    float rd = (denom > 0.f) ? 1.f / denom : 0.f;
    float a0 = 0.f, a1 = 0.f, a2 = 0.f, a3 = 0.f;
    for (int j = r0; j < r1; j++) {
        int e = eidx[j];
        int s = ei[e];
        float alpha = __expf(lbuf4[(size_t)e * 4 + h] - m) * rd;
        ushort4 xv = *(const ushort4*)&xl[(size_t)s * 256 + lane * 4];
        a0 += alpha * bf2f(xv.x); a1 += alpha * bf2f(xv.y);
        a2 += alpha * bf2f(xv.z); a3 += alpha * bf2f(xv.w);
    }
    ushort4 o;
    o.x = f2bf(a0); o.y = f2bf(a1); o.z = f2bf(a2); o.w = f2bf(a3);
    *(ushort4*)&agg[(size_t)n * 256 + lane * 4] = o;
}

// ---------------------------------------------------------------------------
// hid = relu(hid + biasH)  (biasH = b_d1 + conv_bias@W_d1)
__global__ __launch_bounds__(256) void hid_relu_kernel(
    float* __restrict__ hid, const float* __restrict__ biasH)
{
    int g = blockIdx.x * blockDim.x + threadIdx.x;
    if (g >= NN * HID) return;
    hid[g] = fmaxf(hid[g] + biasH[g & (HID - 1)], 0.f);
}

// ---------------------------------------------------------------------------
// out = sigmoid(hid @ W_d2 + b_d2)   hid:[N,256] W:[256,6]
__global__ __launch_bounds__(256) void final_kernel(
    const float* __restrict__ hid, const float* __restrict__ W_d2,
    const float* __restrict__ b_d2, float* __restrict__ out)
{
    int g = blockIdx.x * blockDim.x + threadIdx.x;
    if (g >= NN * 6) return;
    int n = g / 6, j = g % 6;
    float acc = b_d2[j];
    const float4* hp = reinterpret_cast<const float4*>(&hid[(size_t)n * HID]);
#pragma unroll 4
    for (int k4 = 0; k4 < HID / 4; k4++) {
        float4 hv = hp[k4];
        int k = k4 * 4;
        acc += hv.x * W_d2[(k + 0) * 6 + j] + hv.y * W_d2[(k + 1) * 6 + j] +
               hv.z * W_d2[(k + 2) * 6 + j] + hv.w * W_d2[(k + 3) * 6 + j];
    }
    out[g] = 1.f / (1.f + __expf(-acc));
}

// ---------------------------------------------------------------------------
extern "C" void kernel_launch(void* const* d_in, const int* in_sizes, int n_in,
                              void* d_out, int out_size, void* d_ws, size_t ws_size,
                              hipStream_t stream)
{
    const float* x         = (const float*)d_in[0];
    const float* edge_attr = (const float*)d_in[1];
    const float* W_ne = (const float*)d_in[2];  const float* b_ne = (const float*)d_in[3];
    const float* W_ee = (const float*)d_in[4];  const float* b_ee = (const float*)d_in[5];
    const float* W_l  = (const float*)d_in[6];  const float* b_l  = (const float*)d_in[7];
    const float* W_r  = (const float*)d_in[8];  const float* b_r  = (const float*)d_in[9];
    const float* W_e  = (const float*)d_in[10]; const float* b_e  = (const float*)d_in[11];
    const float* att  = (const float*)d_in[12];
    const float* conv_bias = (const float*)d_in[13];
    const float* W_d1 = (const float*)d_in[14]; const float* b_d1 = (const float*)d_in[15];
    const float* W_d2 = (const float*)d_in[16]; const float* b_d2 = (const float*)d_in[17];
    const int*   ei   = (const int*)d_in[18];
    float* out = (float*)d_out;

    const size_t NODEH = (size_t)NN * HID;   // 5.12M
    char* p = (char*)d_ws;
    ushort* h_bf   = (ushort*)p;  p += NODEH * 2;
    ushort* xl_bf  = (ushort*)p;  p += NODEH * 2;
    ushort* xr_bf  = (ushort*)p;  p += NODEH * 2;
    ushort* agg_bf = (ushort*)p;  p += NODEH * 2;
    float*  hid    = (float*)p;   p += NODEH * 4;
    float*  lbuf4  = (float*)p;   p += (size_t)NE * HEADS * 4;
    int*    deg    = (int*)p;     p += (size_t)NN * 4;
    int*    rowptr = (int*)p;     p += (size_t)(NN + 1) * 4;
    int*    cursor = (int*)p;     p += (size_t)NN * 4;
    int*    eidx   = (int*)p;     p += (size_t)NE * 4;
    float*  biasH  = (float*)p;   p += HID * 4;
    ushort* WlT    = (ushort*)p;  p += (size_t)HO * HID * 2;   // [1024][256]
    ushort* WrT    = (ushort*)p;  p += (size_t)HO * HID * 2;
    ushort* WeT    = (ushort*)p;  p += (size_t)HO * HID * 2;
    ushort* Wd1T   = (ushort*)p;  p += (size_t)HID * HO * 2;   // [256][1024]
    if ((size_t)(p - (char*)d_ws) > ws_size) return;  // clean fail, no OOB

    hipMemsetAsync(deg, 0, (size_t)NN * 4, stream);
    hipMemsetAsync(hid, 0, NODEH * 4, stream);

    node_enc_kernel<<<NN, 256, 0, stream>>>(x, W_ne, b_ne, h_bf);
    biasH_kernel<<<1, 256, 0, stream>>>(conv_bias, W_d1, b_d1, biasH);

    transpose_bf16_kernel<<<dim3(HID, HO / 256), 256, 0, stream>>>(W_l,  WlT,  HID, HO);
    transpose_bf16_kernel<<<dim3(HID, HO / 256), 256, 0, stream>>>(W_r,  WrT,  HID, HO);
    transpose_bf16_kernel<<<dim3(HID, HO / 256), 256, 0, stream>>>(W_e,  WeT,  HID, HO);
    transpose_bf16_kernel<<<dim3(HO, HID / 256), 256, 0, stream>>>(W_d1, Wd1T, HO,  HID);

    hist_kernel<<<(NE + 255) / 256, 256, 0, stream>>>(ei, deg);
    scan_kernel<<<1, 64, 0, stream>>>(deg, rowptr, cursor);
    scatter_kernel<<<(NE + 255) / 256, 256, 0, stream>>>(ei, cursor, eidx);

    const int gemmGrid = (NN + 63) / 64;     // 313
    const int edgeGrid = (NE + 63) / 64;     // 1563

    for (int hh = 0; hh < HEADS; hh++) {
        mfma_gemm_kernel<0><<<gemmGrid, 256, 0, stream>>>(
            h_bf, WlT + (size_t)hh * OUT * HID, HID, HID, b_l + hh * OUT, xl_bf, NN);
        mfma_gemm_kernel<0><<<gemmGrid, 256, 0, stream>>>(
            h_bf, WrT + (size_t)hh * OUT * HID, HID, HID, b_r + hh * OUT, xr_bf, NN);

        edge_mfma_logits_kernel<<<edgeGrid, 256, 0, stream>>>(
            edge_attr, W_ee, b_ee, WeT + (size_t)hh * OUT * HID,
            b_e + hh * OUT, att + hh * OUT, xl_bf, xr_bf, ei, lbuf4, hh);

        softmax_agg_kernel<<<(NN + 3) / 4, 256, 0, stream>>>(
            lbuf4, rowptr, eidx, ei, xl_bf, agg_bf, hh);

        mfma_gemm_kernel<1><<<gemmGrid, 256, 0, stream>>>(
            agg_bf, Wd1T + hh * OUT, HO, HID, nullptr, hid, NN);
    }

    hid_relu_kernel<<<(NN * HID + 255) / 256, 256, 0, stream>>>(hid, biasH);
    final_kernel<<<(NN * 6 + 255) / 256, 256, 0, stream>>>(hid, W_d2, b_d2, out);
}

// Round 5
// 995.335 us; speedup vs baseline: 2.1712x; 1.0572x over previous
//
#include <hip/hip_runtime.h>
#include <hip/hip_bf16.h>

#define NN 20000
#define NE 100000
#define HID 256
#define HO 1024   // HEADS*OUT
#define HEADS 4
#define OUT 256

typedef __attribute__((ext_vector_type(8))) short bf16x8;
typedef __attribute__((ext_vector_type(4))) float f32x4;

__device__ inline ushort f2bf(float f) {
    union { float f; unsigned u; } v; v.f = f;
    unsigned r = v.u + 0x7FFFu + ((v.u >> 16) & 1u);  // RNE
    return (ushort)(r >> 16);
}
__device__ inline float bf2f(ushort b) {
    union { unsigned u; float f; } v; v.u = ((unsigned)b) << 16;
    return v.f;
}

// ---------------------------------------------------------------------------
// K1: h_bf = bf16(relu(x @ W_ne + b_ne))   x:[N,7] W:[7,256]
__global__ __launch_bounds__(256) void node_enc_kernel(
    const float* __restrict__ x, const float* __restrict__ W,
    const float* __restrict__ b, ushort* __restrict__ h)
{
    int n = blockIdx.x;
    int c = threadIdx.x;
    __shared__ float xs[8];
    if (threadIdx.x < 7) xs[threadIdx.x] = x[n * 7 + threadIdx.x];
    __syncthreads();
    float acc = b[c];
#pragma unroll
    for (int k = 0; k < 7; k++) acc += xs[k] * W[k * HID + c];
    h[(size_t)n * HID + c] = f2bf(fmaxf(acc, 0.f));
}

// ---------------------------------------------------------------------------
// WT[n][k] = bf16(W[k][n])   W:[K,N]  grid=dim3(K, N/256)
__global__ __launch_bounds__(256) void transpose_bf16_kernel(
    const float* __restrict__ W, ushort* __restrict__ WT, int K, int N)
{
    int k = blockIdx.x;
    int n = blockIdx.y * 256 + threadIdx.x;
    WT[(size_t)n * K + k] = f2bf(W[(size_t)k * N + n]);
}

// ---------------------------------------------------------------------------
// biasH[c] = b_d1[c] + sum_k conv_bias[k] * W_d1[k,c]
__global__ __launch_bounds__(256) void biasH_kernel(
    const float* __restrict__ conv_bias, const float* __restrict__ W_d1,
    const float* __restrict__ b_d1, float* __restrict__ biasH)
{
    int c = threadIdx.x;
    float acc = b_d1[c];
    for (int k = 0; k < HO; k++) acc += conv_bias[k] * W_d1[(size_t)k * HID + c];
    biasH[c] = acc;
}

// ---------------------------------------------------------------------------
// CSR build
__global__ __launch_bounds__(256) void hist_kernel(
    const int* __restrict__ ei, int* __restrict__ deg)
{
    int e = blockIdx.x * blockDim.x + threadIdx.x;
    if (e >= NE) return;
    atomicAdd(&deg[ei[NE + e]], 1);
}

__global__ __launch_bounds__(64) void scan_kernel(
    const int* __restrict__ deg, int* __restrict__ rowptr, int* __restrict__ cursor)
{
    const int CH = 313;   // 64*313 = 20032 >= 20000
    int t = threadIdx.x;
    int start = t * CH, end = min(NN, start + CH);
    int local = 0;
    for (int i = start; i < end; i++) local += deg[i];
    int incl = local;
#pragma unroll
    for (int off = 1; off < 64; off <<= 1) {
        int v = __shfl_up(incl, off);
        if (t >= off) incl += v;
    }
    int run = incl - local;
    for (int i = start; i < end; i++) {
        rowptr[i] = run;
        cursor[i] = run;
        run += deg[i];
    }
    if (t == 63) rowptr[NN] = run;
}

__global__ __launch_bounds__(256) void scatter_kernel(
    const int* __restrict__ ei, int* __restrict__ cursor, int* __restrict__ eidx)
{
    int e = blockIdx.x * blockDim.x + threadIdx.x;
    if (e >= NE) return;
    int d = ei[NE + e];
    int pos = atomicAdd(&cursor[d], 1);
    eidx[pos] = e;
}

// ---------------------------------------------------------------------------
// MFMA GEMM: C[M,256] = A[M,256] @ BT[256 cols][256 k]^T  (BT row n = col n of B)
// A tile staged in LDS (coalesced). MODE 0: C bf16 = res + bias. MODE 1: C f32 +=.
template <int MODE>
__global__ __launch_bounds__(256) void mfma_gemm_kernel(
    const ushort* __restrict__ A, const ushort* __restrict__ BT, int ldBT,
    const float* __restrict__ bias, void* __restrict__ Cv, int M)
{
    __shared__ __align__(16) ushort As[64][264];
    int t = threadIdx.x, w = t >> 6, lane = t & 63;
    int l15 = lane & 15, l4 = lane >> 4;
    int row0 = blockIdx.x * 64;
    {   // stage A tile: thread t -> row t>>2, 128B chunk (t&3)
        int r = t >> 2, c0 = (t & 3) * 64;
        int row = row0 + r;
        if (row < M) {
            const ushort* src = &A[(size_t)row * 256 + c0];
#pragma unroll
            for (int c = 0; c < 8; c++)
                *(bf16x8*)&As[r][c0 + c * 8] = *(const bf16x8*)&src[c * 8];
        } else {
            bf16x8 z = (bf16x8){0, 0, 0, 0, 0, 0, 0, 0};
#pragma unroll
            for (int c = 0; c < 8; c++) *(bf16x8*)&As[r][c0 + c * 8] = z;
        }
    }
    __syncthreads();
    f32x4 acc[4][4] = {};
    for (int k0 = 0; k0 < 256; k0 += 32) {
        bf16x8 a[4], b[4];
#pragma unroll
        for (int rt = 0; rt < 4; rt++)
            a[rt] = *(const bf16x8*)&As[rt * 16 + l15][k0 + l4 * 8];
#pragma unroll
        for (int ct = 0; ct < 4; ct++) {
            int n = w * 64 + ct * 16 + l15;
            b[ct] = *(const bf16x8*)&BT[(size_t)n * ldBT + k0 + l4 * 8];
        }
#pragma unroll
        for (int rt = 0; rt < 4; rt++)
#pragma unroll
            for (int ct = 0; ct < 4; ct++)
                acc[rt][ct] = __builtin_amdgcn_mfma_f32_16x16x32_bf16(
                    a[rt], b[ct], acc[rt][ct], 0, 0, 0);
    }
    if constexpr (MODE == 0) {
        ushort* C = (ushort*)Cv;
        float bv[4];
#pragma unroll
        for (int ct = 0; ct < 4; ct++) bv[ct] = bias[w * 64 + ct * 16 + l15];
#pragma unroll
        for (int rt = 0; rt < 4; rt++)
#pragma unroll
            for (int ct = 0; ct < 4; ct++)
#pragma unroll
                for (int r = 0; r < 4; r++) {
                    int row = row0 + rt * 16 + l4 * 4 + r;
                    if (row < M)
                        C[(size_t)row * 256 + w * 64 + ct * 16 + l15] =
                            f2bf(acc[rt][ct][r] + bv[ct]);
                }
    } else {
        float* C = (float*)Cv;
#pragma unroll
        for (int rt = 0; rt < 4; rt++)
#pragma unroll
            for (int ct = 0; ct < 4; ct++)
#pragma unroll
                for (int r = 0; r < 4; r++) {
                    int row = row0 + rt * 16 + l4 * 4 + r;
                    if (row < M)
                        C[(size_t)row * 256 + w * 64 + ct * 16 + l15] += acc[rt][ct][r];
                }
    }
}

// ---------------------------------------------------------------------------
// Fused edge kernel (per head): 64 edges/block, 4 waves.
// A: e_enc [64,256] bf16 -> LDS (K=7 recompute).
// B: e_h via MFMA vs WeT head slice (acc[4][4] f32x4).
// C: per 16-edge group, stage xl[src]/xr[dst] rows into LDS (coalesced 16B),
//    then logit = sum_c lrelu(e_h + b_e + xl + xr) * att from LDS.
// D: 16-lane shfl + cross-wave reduce -> lbuf4[e*4+h].
__global__ __launch_bounds__(256) void edge_mfma_logits_kernel(
    const float* __restrict__ edge_attr, const float* __restrict__ W_ee,
    const float* __restrict__ b_ee, const ushort* __restrict__ WeTh,
    const float* __restrict__ b_e_h, const float* __restrict__ att_h,
    const ushort* __restrict__ xl, const ushort* __restrict__ xr,
    const int* __restrict__ ei, float* __restrict__ lbuf4, int h)
{
    __shared__ __align__(16) ushort As[64][264];   // 33.8 KB; reused as XL/XR
    __shared__ float ea[448];
    __shared__ int sArr[64], dArr[64];
    __shared__ float red[4][64];
    ushort (*XL)[264] = As;        // rows 0..15 region
    ushort (*XR)[264] = As + 16;   // rows 16..31 region
    int e0 = blockIdx.x * 64;
    int t = threadIdx.x, w = t >> 6, lane = t & 63;
    int l15 = lane & 15, l4 = lane >> 4;
    int nval = NE - e0; if (nval > 64) nval = 64;

    for (int i = t; i < 448; i += 256)
        ea[i] = (i < nval * 7) ? edge_attr[(size_t)e0 * 7 + i] : 0.f;
    if (t < 64) {
        int e = e0 + t;
        sArr[t] = (t < nval) ? ei[e] : 0;
        dArr[t] = (t < nval) ? ei[NE + e] : 0;
    }
    float w7[7];
#pragma unroll
    for (int k = 0; k < 7; k++) w7[k] = W_ee[k * HID + t];
    float bee = b_ee[t];
    __syncthreads();
#pragma unroll 4
    for (int r = 0; r < 64; r++) {
        float acc = bee;
#pragma unroll
        for (int k = 0; k < 7; k++) acc += w7[k] * ea[r * 7 + k];
        As[r][t] = f2bf(fmaxf(acc, 0.f));
    }
    __syncthreads();

    f32x4 acc[4][4] = {};
    for (int k0 = 0; k0 < 256; k0 += 32) {
        bf16x8 a[4], b[4];
#pragma unroll
        for (int rt = 0; rt < 4; rt++)
            a[rt] = *(const bf16x8*)&As[rt * 16 + l15][k0 + l4 * 8];
#pragma unroll
        for (int ct = 0; ct < 4; ct++) {
            int n = w * 64 + ct * 16 + l15;
            b[ct] = *(const bf16x8*)&WeTh[(size_t)n * 256 + k0 + l4 * 8];
        }
#pragma unroll
        for (int rt = 0; rt < 4; rt++)
#pragma unroll
            for (int ct = 0; ct < 4; ct++)
                acc[rt][ct] = __builtin_amdgcn_mfma_f32_16x16x32_bf16(
                    a[rt], b[ct], acc[rt][ct], 0, 0, 0);
    }

    float bev[4], atv[4];
#pragma unroll
    for (int ct = 0; ct < 4; ct++) {
        int col = w * 64 + ct * 16 + l15;
        bev[ct] = b_e_h[col];
        atv[ct] = att_h[col];
    }
    __syncthreads();   // As (e_enc) fully consumed; safe to reuse as XL/XR

    float lp[4][4];
#pragma unroll
    for (int rt = 0; rt < 4; rt++)
#pragma unroll
        for (int r = 0; r < 4; r++) lp[rt][r] = 0.f;

    int sli = t >> 4;           // staging row 0..15
    int sch = (t & 15) * 16;    // staging col chunk (16 ushorts = 32B)
    for (int rt = 0; rt < 4; rt++) {
        {   // stage 16 xl rows + 16 xr rows, coalesced 16B loads
            int sRow = sArr[rt * 16 + sli], dRow = dArr[rt * 16 + sli];
            bf16x8 v0 = *(const bf16x8*)&xl[(size_t)sRow * 256 + sch];
            bf16x8 v1 = *(const bf16x8*)&xl[(size_t)sRow * 256 + sch + 8];
            bf16x8 v2 = *(const bf16x8*)&xr[(size_t)dRow * 256 + sch];
            bf16x8 v3 = *(const bf16x8*)&xr[(size_t)dRow * 256 + sch + 8];
            *(bf16x8*)&XL[sli][sch]     = v0;
            *(bf16x8*)&XL[sli][sch + 8] = v1;
            *(bf16x8*)&XR[sli][sch]     = v2;
            *(bf16x8*)&XR[sli][sch + 8] = v3;
        }
        __syncthreads();
#pragma unroll
        for (int r = 0; r < 4; r++) {
            int li = l4 * 4 + r;
            float p = 0.f;
#pragma unroll
            for (int ct = 0; ct < 4; ct++) {
                int col = w * 64 + ct * 16 + l15;
                float z = acc[rt][ct][r] + bev[ct] +
                          bf2f(XL[li][col]) + bf2f(XR[li][col]);
                z = (z > 0.f) ? z : 0.2f * z;
                p += z * atv[ct];
            }
            lp[rt][r] += p;
        }
        __syncthreads();
    }

#pragma unroll
    for (int off = 1; off < 16; off <<= 1)
#pragma unroll
        for (int rt = 0; rt < 4; rt++)
#pragma unroll
            for (int r = 0; r < 4; r++)
                lp[rt][r] += __shfl_xor(lp[rt][r], off);
    if (l15 == 0)
#pragma unroll
        for (int rt = 0; rt < 4; rt++)
#pragma unroll
            for (int r = 0; r < 4; r++)
                red[w][rt * 16 + l4 * 4 + r] = lp[rt][r];
    __syncthreads();
    if (t < nval) {
        float v = red[0][t] + red[1][t] + red[2][t] + red[3][t];
        lbuf4[(size_t)(e0 + t) * 4 + h] = v;
    }
}

// ---------------------------------------------------------------------------
// Fused segment softmax + aggregation (per head). One wave per dst node.
__global__ __launch_bounds__(256) void softmax_agg_kernel(
    const float* __restrict__ lbuf4, const int* __restrict__ rowptr,
    const int* __restrict__ eidx, const int* __restrict__ ei,
    const ushort* __restrict__ xl, ushort* __restrict__ agg, int h)
{
    int wv = threadIdx.x >> 6, lane = threadIdx.x & 63;
    int n = blockIdx.x * 4 + wv;
    if (n >= NN) return;
    int r0 = rowptr[n], r1 = rowptr[n + 1];
    float m = -3.4e38f;
    for (int j = r0; j < r1; j++)
        m = fmaxf(m, lbuf4[(size_t)eidx[j] * 4 + h]);
    float denom = 0.f;
    for (int j = r0; j < r1; j++)
        denom += __expf(lbuf4[(size_t)eidx[j] * 4 + h] - m);
    float rd = (denom > 0.f) ? 1.f / denom : 0.f;
    float a0 = 0.f, a1 = 0.f, a2 = 0.f, a3 = 0.f;
    for (int j = r0; j < r1; j++) {
        int e = eidx[j];
        int s = ei[e];
        float alpha = __expf(lbuf4[(size_t)e * 4 + h] - m) * rd;
        ushort4 xv = *(const ushort4*)&xl[(size_t)s * 256 + lane * 4];
        a0 += alpha * bf2f(xv.x); a1 += alpha * bf2f(xv.y);
        a2 += alpha * bf2f(xv.z); a3 += alpha * bf2f(xv.w);
    }
    ushort4 o;
    o.x = f2bf(a0); o.y = f2bf(a1); o.z = f2bf(a2); o.w = f2bf(a3);
    *(ushort4*)&agg[(size_t)n * 256 + lane * 4] = o;
}

// ---------------------------------------------------------------------------
// hid = relu(hid + biasH)
__global__ __launch_bounds__(256) void hid_relu_kernel(
    float* __restrict__ hid, const float* __restrict__ biasH)
{
    int g = blockIdx.x * blockDim.x + threadIdx.x;
    if (g >= NN * HID) return;
    hid[g] = fmaxf(hid[g] + biasH[g & (HID - 1)], 0.f);
}

// ---------------------------------------------------------------------------
// out = sigmoid(hid @ W_d2 + b_d2)
__global__ __launch_bounds__(256) void final_kernel(
    const float* __restrict__ hid, const float* __restrict__ W_d2,
    const float* __restrict__ b_d2, float* __restrict__ out)
{
    int g = blockIdx.x * blockDim.x + threadIdx.x;
    if (g >= NN * 6) return;
    int n = g / 6, j = g % 6;
    float acc = b_d2[j];
    const float4* hp = reinterpret_cast<const float4*>(&hid[(size_t)n * HID]);
#pragma unroll 4
    for (int k4 = 0; k4 < HID / 4; k4++) {
        float4 hv = hp[k4];
        int k = k4 * 4;
        acc += hv.x * W_d2[(k + 0) * 6 + j] + hv.y * W_d2[(k + 1) * 6 + j] +
               hv.z * W_d2[(k + 2) * 6 + j] + hv.w * W_d2[(k + 3) * 6 + j];
    }
    out[g] = 1.f / (1.f + __expf(-acc));
}

// ---------------------------------------------------------------------------
extern "C" void kernel_launch(void* const* d_in, const int* in_sizes, int n_in,
                              void* d_out, int out_size, void* d_ws, size_t ws_size,
                              hipStream_t stream)
{
    const float* x         = (const float*)d_in[0];
    const float* edge_attr = (const float*)d_in[1];
    const float* W_ne = (const float*)d_in[2];  const float* b_ne = (const float*)d_in[3];
    const float* W_ee = (const float*)d_in[4];  const float* b_ee = (const float*)d_in[5];
    const float* W_l  = (const float*)d_in[6];  const float* b_l  = (const float*)d_in[7];
    const float* W_r  = (const float*)d_in[8];  const float* b_r  = (const float*)d_in[9];
    const float* W_e  = (const float*)d_in[10]; const float* b_e  = (const float*)d_in[11];
    const float* att  = (const float*)d_in[12];
    const float* conv_bias = (const float*)d_in[13];
    const float* W_d1 = (const float*)d_in[14]; const float* b_d1 = (const float*)d_in[15];
    const float* W_d2 = (const float*)d_in[16]; const float* b_d2 = (const float*)d_in[17];
    const int*   ei   = (const int*)d_in[18];
    float* out = (float*)d_out;

    const size_t NODEH = (size_t)NN * HID;   // 5.12M
    char* p = (char*)d_ws;
    ushort* h_bf   = (ushort*)p;  p += NODEH * 2;
    ushort* xl_bf  = (ushort*)p;  p += NODEH * 2;
    ushort* xr_bf  = (ushort*)p;  p += NODEH * 2;
    ushort* agg_bf = (ushort*)p;  p += NODEH * 2;
    float*  hid    = (float*)p;   p += NODEH * 4;
    float*  lbuf4  = (float*)p;   p += (size_t)NE * HEADS * 4;
    int*    deg    = (int*)p;     p += (size_t)NN * 4;
    int*    rowptr = (int*)p;     p += (size_t)(NN + 1) * 4;
    int*    cursor = (int*)p;     p += (size_t)NN * 4;
    int*    eidx   = (int*)p;     p += (size_t)NE * 4;
    float*  biasH  = (float*)p;   p += HID * 4;
    ushort* WlT    = (ushort*)p;  p += (size_t)HO * HID * 2;   // [1024][256]
    ushort* WrT    = (ushort*)p;  p += (size_t)HO * HID * 2;
    ushort* WeT    = (ushort*)p;  p += (size_t)HO * HID * 2;
    ushort* Wd1T   = (ushort*)p;  p += (size_t)HID * HO * 2;   // [256][1024]
    if ((size_t)(p - (char*)d_ws) > ws_size) return;  // clean fail, no OOB

    hipMemsetAsync(deg, 0, (size_t)NN * 4, stream);
    hipMemsetAsync(hid, 0, NODEH * 4, stream);

    node_enc_kernel<<<NN, 256, 0, stream>>>(x, W_ne, b_ne, h_bf);
    biasH_kernel<<<1, 256, 0, stream>>>(conv_bias, W_d1, b_d1, biasH);

    transpose_bf16_kernel<<<dim3(HID, HO / 256), 256, 0, stream>>>(W_l,  WlT,  HID, HO);
    transpose_bf16_kernel<<<dim3(HID, HO / 256), 256, 0, stream>>>(W_r,  WrT,  HID, HO);
    transpose_bf16_kernel<<<dim3(HID, HO / 256), 256, 0, stream>>>(W_e,  WeT,  HID, HO);
    transpose_bf16_kernel<<<dim3(HO, HID / 256), 256, 0, stream>>>(W_d1, Wd1T, HO,  HID);

    hist_kernel<<<(NE + 255) / 256, 256, 0, stream>>>(ei, deg);
    scan_kernel<<<1, 64, 0, stream>>>(deg, rowptr, cursor);
    scatter_kernel<<<(NE + 255) / 256, 256, 0, stream>>>(ei, cursor, eidx);

    const int gemmGrid = (NN + 63) / 64;     // 313
    const int edgeGrid = (NE + 63) / 64;     // 1563

    for (int hh = 0; hh < HEADS; hh++) {
        mfma_gemm_kernel<0><<<gemmGrid, 256, 0, stream>>>(
            h_bf, WlT + (size_t)hh * OUT * HID, HID, b_l + hh * OUT, xl_bf, NN);
        mfma_gemm_kernel<0><<<gemmGrid, 256, 0, stream>>>(
            h_bf, WrT + (size_t)hh * OUT * HID, HID, b_r + hh * OUT, xr_bf, NN);

        edge_mfma_logits_kernel<<<edgeGrid, 256, 0, stream>>>(
            edge_attr, W_ee, b_ee, WeT + (size_t)hh * OUT * HID,
            b_e + hh * OUT, att + hh * OUT, xl_bf, xr_bf, ei, lbuf4, hh);

        softmax_agg_kernel<<<(NN + 3) / 4, 256, 0, stream>>>(
            lbuf4, rowptr, eidx, ei, xl_bf, agg_bf, hh);

        mfma_gemm_kernel<1><<<gemmGrid, 256, 0, stream>>>(
            agg_bf, Wd1T + hh * OUT, HO, nullptr, hid, NN);
    }

    hid_relu_kernel<<<(NN * HID + 255) / 256, 256, 0, stream>>>(hid, biasH);
    final_kernel<<<(NN * 6 + 255) / 256, 256, 0, stream>>>(hid, W_d2, b_d2, out);
}

// Round 6
// 992.513 us; speedup vs baseline: 2.1773x; 1.0028x over previous
//
#include <hip/hip_runtime.h>
#include <hip/hip_bf16.h>

#define NN 20000
#define NE 100000
#define HID 256
#define HO 1024   // HEADS*OUT
#define HEADS 4
#define OUT 256

typedef __attribute__((ext_vector_type(8))) short bf16x8;
typedef __attribute__((ext_vector_type(4))) float f32x4;

__device__ inline ushort f2bf(float f) {
    union { float f; unsigned u; } v; v.f = f;
    unsigned r = v.u + 0x7FFFu + ((v.u >> 16) & 1u);  // RNE
    return (ushort)(r >> 16);
}
__device__ inline float bf2f(ushort b) {
    union { unsigned u; float f; } v; v.u = ((unsigned)b) << 16;
    return v.f;
}

// ---------------------------------------------------------------------------
// K1: h_bf = bf16(relu(x @ W_ne + b_ne))   x:[N,7] W:[7,256]
__global__ __launch_bounds__(256) void node_enc_kernel(
    const float* __restrict__ x, const float* __restrict__ W,
    const float* __restrict__ b, ushort* __restrict__ h)
{
    int n = blockIdx.x;
    int c = threadIdx.x;
    __shared__ float xs[8];
    if (threadIdx.x < 7) xs[threadIdx.x] = x[n * 7 + threadIdx.x];
    __syncthreads();
    float acc = b[c];
#pragma unroll
    for (int k = 0; k < 7; k++) acc += xs[k] * W[k * HID + c];
    h[(size_t)n * HID + c] = f2bf(fmaxf(acc, 0.f));
}

// ---------------------------------------------------------------------------
// WT[n][k] = bf16(W[k][n])   W:[K,N]  grid=dim3(K, N/256)
__global__ __launch_bounds__(256) void transpose_bf16_kernel(
    const float* __restrict__ W, ushort* __restrict__ WT, int K, int N)
{
    int k = blockIdx.x;
    int n = blockIdx.y * 256 + threadIdx.x;
    WT[(size_t)n * K + k] = f2bf(W[(size_t)k * N + n]);
}

// ---------------------------------------------------------------------------
// biasH[c] = b_d1[c] + sum_k conv_bias[k] * W_d1[k,c]
__global__ __launch_bounds__(256) void biasH_kernel(
    const float* __restrict__ conv_bias, const float* __restrict__ W_d1,
    const float* __restrict__ b_d1, float* __restrict__ biasH)
{
    int c = threadIdx.x;
    float acc = b_d1[c];
    for (int k = 0; k < HO; k++) acc += conv_bias[k] * W_d1[(size_t)k * HID + c];
    biasH[c] = acc;
}

// ---------------------------------------------------------------------------
// CSR build
__global__ __launch_bounds__(256) void hist_kernel(
    const int* __restrict__ ei, int* __restrict__ deg)
{
    int e = blockIdx.x * blockDim.x + threadIdx.x;
    if (e >= NE) return;
    atomicAdd(&deg[ei[NE + e]], 1);
}

__global__ __launch_bounds__(64) void scan_kernel(
    const int* __restrict__ deg, int* __restrict__ rowptr, int* __restrict__ cursor)
{
    const int CH = 313;   // 64*313 = 20032 >= 20000
    int t = threadIdx.x;
    int start = t * CH, end = min(NN, start + CH);
    int local = 0;
    for (int i = start; i < end; i++) local += deg[i];
    int incl = local;
#pragma unroll
    for (int off = 1; off < 64; off <<= 1) {
        int v = __shfl_up(incl, off);
        if (t >= off) incl += v;
    }
    int run = incl - local;
    for (int i = start; i < end; i++) {
        rowptr[i] = run;
        cursor[i] = run;
        run += deg[i];
    }
    if (t == 63) rowptr[NN] = run;
}

__global__ __launch_bounds__(256) void scatter_kernel(
    const int* __restrict__ ei, int* __restrict__ cursor, int* __restrict__ eidx)
{
    int e = blockIdx.x * blockDim.x + threadIdx.x;
    if (e >= NE) return;
    int d = ei[NE + e];
    int pos = atomicAdd(&cursor[d], 1);
    eidx[pos] = e;
}

// ---------------------------------------------------------------------------
// MFMA GEMM: C[M,256] = A[M,256] @ BT[256 cols][256 k]^T  (BT row n = col n of B)
// A tile staged in LDS (coalesced). MODE 0: C bf16 = res + bias. MODE 1: C f32 +=.
template <int MODE>
__global__ __launch_bounds__(256) void mfma_gemm_kernel(
    const ushort* __restrict__ A, const ushort* __restrict__ BT, int ldBT,
    const float* __restrict__ bias, void* __restrict__ Cv, int M)
{
    __shared__ __align__(16) ushort As[64][264];
    int t = threadIdx.x, w = t >> 6, lane = t & 63;
    int l15 = lane & 15, l4 = lane >> 4;
    int row0 = blockIdx.x * 64;
    {   // stage A tile: thread t -> row t>>2, 128B chunk (t&3)
        int r = t >> 2, c0 = (t & 3) * 64;
        int row = row0 + r;
        if (row < M) {
            const ushort* src = &A[(size_t)row * 256 + c0];
#pragma unroll
            for (int c = 0; c < 8; c++)
                *(bf16x8*)&As[r][c0 + c * 8] = *(const bf16x8*)&src[c * 8];
        } else {
            bf16x8 z = (bf16x8){0, 0, 0, 0, 0, 0, 0, 0};
#pragma unroll
            for (int c = 0; c < 8; c++) *(bf16x8*)&As[r][c0 + c * 8] = z;
        }
    }
    __syncthreads();
    f32x4 acc[4][4] = {};
    for (int k0 = 0; k0 < 256; k0 += 32) {
        bf16x8 a[4], b[4];
#pragma unroll
        for (int rt = 0; rt < 4; rt++)
            a[rt] = *(const bf16x8*)&As[rt * 16 + l15][k0 + l4 * 8];
#pragma unroll
        for (int ct = 0; ct < 4; ct++) {
            int n = w * 64 + ct * 16 + l15;
            b[ct] = *(const bf16x8*)&BT[(size_t)n * ldBT + k0 + l4 * 8];
        }
#pragma unroll
        for (int rt = 0; rt < 4; rt++)
#pragma unroll
            for (int ct = 0; ct < 4; ct++)
                acc[rt][ct] = __builtin_amdgcn_mfma_f32_16x16x32_bf16(
                    a[rt], b[ct], acc[rt][ct], 0, 0, 0);
    }
    if constexpr (MODE == 0) {
        ushort* C = (ushort*)Cv;
        float bv[4];
#pragma unroll
        for (int ct = 0; ct < 4; ct++) bv[ct] = bias[w * 64 + ct * 16 + l15];
#pragma unroll
        for (int rt = 0; rt < 4; rt++)
#pragma unroll
            for (int ct = 0; ct < 4; ct++)
#pragma unroll
                for (int r = 0; r < 4; r++) {
                    int row = row0 + rt * 16 + l4 * 4 + r;
                    if (row < M)
                        C[(size_t)row * 256 + w * 64 + ct * 16 + l15] =
                            f2bf(acc[rt][ct][r] + bv[ct]);
                }
    } else {
        float* C = (float*)Cv;
#pragma unroll
        for (int rt = 0; rt < 4; rt++)
#pragma unroll
            for (int ct = 0; ct < 4; ct++)
#pragma unroll
                for (int r = 0; r < 4; r++) {
                    int row = row0 + rt * 16 + l4 * 4 + r;
                    if (row < M)
                        C[(size_t)row * 256 + w * 64 + ct * 16 + l15] += acc[rt][ct][r];
                }
    }
}

// ---------------------------------------------------------------------------
// Fused edge kernel (per head): 64 edges/block, 4 waves.
// Prefetch (T14): issue ALL xl[src]/xr[dst] gather loads into registers at the
// top, so their ~900cy latency hides under e_enc VALU + MFMA compute.
// A: e_enc [64,256] bf16 -> LDS (K=7 recompute).
// B: e_h via MFMA vs WeT head slice.
// C: per 16-edge group, write prefetched regs -> LDS (coalesced), then
//    logit = sum_c lrelu(e_h + b_e + xl + xr) * att from LDS.
// D: 16-lane shfl + cross-wave reduce -> lbuf4[e*4+h].
__global__ __launch_bounds__(256) void edge_mfma_logits_kernel(
    const float* __restrict__ edge_attr, const float* __restrict__ W_ee,
    const float* __restrict__ b_ee, const ushort* __restrict__ WeTh,
    const float* __restrict__ b_e_h, const float* __restrict__ att_h,
    const ushort* __restrict__ xl, const ushort* __restrict__ xr,
    const int* __restrict__ ei, float* __restrict__ lbuf4, int h)
{
    __shared__ __align__(16) ushort As[64][264];   // 33.8 KB; reused as XL/XR
    __shared__ float ea[448];
    __shared__ int sArr[64], dArr[64];
    __shared__ float red[4][64];
    ushort (*XL)[264] = As;        // rows 0..15 region
    ushort (*XR)[264] = As + 16;   // rows 16..31 region
    int e0 = blockIdx.x * 64;
    int t = threadIdx.x, w = t >> 6, lane = t & 63;
    int l15 = lane & 15, l4 = lane >> 4;
    int nval = NE - e0; if (nval > 64) nval = 64;

    for (int i = t; i < 448; i += 256)
        ea[i] = (i < nval * 7) ? edge_attr[(size_t)e0 * 7 + i] : 0.f;
    if (t < 64) {
        int e = e0 + t;
        sArr[t] = (t < nval) ? ei[e] : 0;
        dArr[t] = (t < nval) ? ei[NE + e] : 0;
    }
    float w7[7];
#pragma unroll
    for (int k = 0; k < 7; k++) w7[k] = W_ee[k * HID + t];
    float bee = b_ee[t];
    __syncthreads();

    // ---- T14 prefetch: all 4 groups' gather rows -> registers (64 VGPR) ----
    int sli = t >> 4;           // staging row 0..15 within group
    int sch = (t & 15) * 16;    // staging col chunk (16 ushorts = 32B)
    bf16x8 pf0[4], pf1[4], pf2[4], pf3[4];   // [group]: xl lo, xl hi, xr lo, xr hi
#pragma unroll
    for (int rt = 0; rt < 4; rt++) {
        int sRow = sArr[rt * 16 + sli], dRow = dArr[rt * 16 + sli];
        const ushort* ps = &xl[(size_t)sRow * 256 + sch];
        const ushort* pd = &xr[(size_t)dRow * 256 + sch];
        pf0[rt] = *(const bf16x8*)ps;
        pf1[rt] = *(const bf16x8*)(ps + 8);
        pf2[rt] = *(const bf16x8*)pd;
        pf3[rt] = *(const bf16x8*)(pd + 8);
    }

    // ---- phase A: e_enc (latency of prefetch hides under this + MFMA) ----
#pragma unroll 4
    for (int r = 0; r < 64; r++) {
        float acc = bee;
#pragma unroll
        for (int k = 0; k < 7; k++) acc += w7[k] * ea[r * 7 + k];
        As[r][t] = f2bf(fmaxf(acc, 0.f));
    }
    __syncthreads();

    // ---- phase B: MFMA ----
    f32x4 acc[4][4] = {};
    for (int k0 = 0; k0 < 256; k0 += 32) {
        bf16x8 a[4], b[4];
#pragma unroll
        for (int rt = 0; rt < 4; rt++)
            a[rt] = *(const bf16x8*)&As[rt * 16 + l15][k0 + l4 * 8];
#pragma unroll
        for (int ct = 0; ct < 4; ct++) {
            int n = w * 64 + ct * 16 + l15;
            b[ct] = *(const bf16x8*)&WeTh[(size_t)n * 256 + k0 + l4 * 8];
        }
#pragma unroll
        for (int rt = 0; rt < 4; rt++)
#pragma unroll
            for (int ct = 0; ct < 4; ct++)
                acc[rt][ct] = __builtin_amdgcn_mfma_f32_16x16x32_bf16(
                    a[rt], b[ct], acc[rt][ct], 0, 0, 0);
    }

    float bev[4], atv[4];
#pragma unroll
    for (int ct = 0; ct < 4; ct++) {
        int col = w * 64 + ct * 16 + l15;
        bev[ct] = b_e_h[col];
        atv[ct] = att_h[col];
    }
    __syncthreads();   // As (e_enc) fully consumed; safe to reuse as XL/XR

    // ---- phase C: per-group write prefetched regs -> LDS, compute logits ----
    float lp[4][4];
#pragma unroll
    for (int rt = 0; rt < 4; rt++) {
        *(bf16x8*)&XL[sli][sch]     = pf0[rt];
        *(bf16x8*)&XL[sli][sch + 8] = pf1[rt];
        *(bf16x8*)&XR[sli][sch]     = pf2[rt];
        *(bf16x8*)&XR[sli][sch + 8] = pf3[rt];
        __syncthreads();
#pragma unroll
        for (int r = 0; r < 4; r++) {
            int li = l4 * 4 + r;
            float p = 0.f;
#pragma unroll
            for (int ct = 0; ct < 4; ct++) {
                int col = w * 64 + ct * 16 + l15;
                float z = acc[rt][ct][r] + bev[ct] +
                          bf2f(XL[li][col]) + bf2f(XR[li][col]);
                z = (z > 0.f) ? z : 0.2f * z;
                p += z * atv[ct];
            }
            lp[rt][r] = p;
        }
        __syncthreads();
    }

#pragma unroll
    for (int off = 1; off < 16; off <<= 1)
#pragma unroll
        for (int rt = 0; rt < 4; rt++)
#pragma unroll
            for (int r = 0; r < 4; r++)
                lp[rt][r] += __shfl_xor(lp[rt][r], off);
    if (l15 == 0)
#pragma unroll
        for (int rt = 0; rt < 4; rt++)
#pragma unroll
            for (int r = 0; r < 4; r++)
                red[w][rt * 16 + l4 * 4 + r] = lp[rt][r];
    __syncthreads();
    if (t < nval) {
        float v = red[0][t] + red[1][t] + red[2][t] + red[3][t];
        lbuf4[(size_t)(e0 + t) * 4 + h] = v;
    }
}

// ---------------------------------------------------------------------------
// Fused segment softmax + aggregation (per head). One wave per dst node.
__global__ __launch_bounds__(256) void softmax_agg_kernel(
    const float* __restrict__ lbuf4, const int* __restrict__ rowptr,
    const int* __restrict__ eidx, const int* __restrict__ ei,
    const ushort* __restrict__ xl, ushort* __restrict__ agg, int h)
{
    int wv = threadIdx.x >> 6, lane = threadIdx.x & 63;
    int n = blockIdx.x * 4 + wv;
    if (n >= NN) return;
    int r0 = rowptr[n], r1 = rowptr[n + 1];
    float m = -3.4e38f;
    for (int j = r0; j < r1; j++)
        m = fmaxf(m, lbuf4[(size_t)eidx[j] * 4 + h]);
    float denom = 0.f;
    for (int j = r0; j < r1; j++)
        denom += __expf(lbuf4[(size_t)eidx[j] * 4 + h] - m);
    float rd = (denom > 0.f) ? 1.f / denom : 0.f;
    float a0 = 0.f, a1 = 0.f, a2 = 0.f, a3 = 0.f;
    for (int j = r0; j < r1; j++) {
        int e = eidx[j];
        int s = ei[e];
        float alpha = __expf(lbuf4[(size_t)e * 4 + h] - m) * rd;
        ushort4 xv = *(const ushort4*)&xl[(size_t)s * 256 + lane * 4];
        a0 += alpha * bf2f(xv.x); a1 += alpha * bf2f(xv.y);
        a2 += alpha * bf2f(xv.z); a3 += alpha * bf2f(xv.w);
    }
    ushort4 o;
    o.x = f2bf(a0); o.y = f2bf(a1); o.z = f2bf(a2); o.w = f2bf(a3);
    *(ushort4*)&agg[(size_t)n * 256 + lane * 4] = o;
}

// ---------------------------------------------------------------------------
// hid = relu(hid + biasH)
__global__ __launch_bounds__(256) void hid_relu_kernel(
    float* __restrict__ hid, const float* __restrict__ biasH)
{
    int g = blockIdx.x * blockDim.x + threadIdx.x;
    if (g >= NN * HID) return;
    hid[g] = fmaxf(hid[g] + biasH[g & (HID - 1)], 0.f);
}

// ---------------------------------------------------------------------------
// out = sigmoid(hid @ W_d2 + b_d2)
__global__ __launch_bounds__(256) void final_kernel(
    const float* __restrict__ hid, const float* __restrict__ W_d2,
    const float* __restrict__ b_d2, float* __restrict__ out)
{
    int g = blockIdx.x * blockDim.x + threadIdx.x;
    if (g >= NN * 6) return;
    int n = g / 6, j = g % 6;
    float acc = b_d2[j];
    const float4* hp = reinterpret_cast<const float4*>(&hid[(size_t)n * HID]);
#pragma unroll 4
    for (int k4 = 0; k4 < HID / 4; k4++) {
        float4 hv = hp[k4];
        int k = k4 * 4;
        acc += hv.x * W_d2[(k + 0) * 6 + j] + hv.y * W_d2[(k + 1) * 6 + j] +
               hv.z * W_d2[(k + 2) * 6 + j] + hv.w * W_d2[(k + 3) * 6 + j];
    }
    out[g] = 1.f / (1.f + __expf(-acc));
}

// ---------------------------------------------------------------------------
extern "C" void kernel_launch(void* const* d_in, const int* in_sizes, int n_in,
                              void* d_out, int out_size, void* d_ws, size_t ws_size,
                              hipStream_t stream)
{
    const float* x         = (const float*)d_in[0];
    const float* edge_attr = (const float*)d_in[1];
    const float* W_ne = (const float*)d_in[2];  const float* b_ne = (const float*)d_in[3];
    const float* W_ee = (const float*)d_in[4];  const float* b_ee = (const float*)d_in[5];
    const float* W_l  = (const float*)d_in[6];  const float* b_l  = (const float*)d_in[7];
    const float* W_r  = (const float*)d_in[8];  const float* b_r  = (const float*)d_in[9];
    const float* W_e  = (const float*)d_in[10]; const float* b_e  = (const float*)d_in[11];
    const float* att  = (const float*)d_in[12];
    const float* conv_bias = (const float*)d_in[13];
    const float* W_d1 = (const float*)d_in[14]; const float* b_d1 = (const float*)d_in[15];
    const float* W_d2 = (const float*)d_in[16]; const float* b_d2 = (const float*)d_in[17];
    const int*   ei   = (const int*)d_in[18];
    float* out = (float*)d_out;

    const size_t NODEH = (size_t)NN * HID;   // 5.12M
    char* p = (char*)d_ws;
    ushort* h_bf   = (ushort*)p;  p += NODEH * 2;
    ushort* xl_bf  = (ushort*)p;  p += NODEH * 2;
    ushort* xr_bf  = (ushort*)p;  p += NODEH * 2;
    ushort* agg_bf = (ushort*)p;  p += NODEH * 2;
    float*  hid    = (float*)p;   p += NODEH * 4;
    float*  lbuf4  = (float*)p;   p += (size_t)NE * HEADS * 4;
    int*    deg    = (int*)p;     p += (size_t)NN * 4;
    int*    rowptr = (int*)p;     p += (size_t)(NN + 1) * 4;
    int*    cursor = (int*)p;     p += (size_t)NN * 4;
    int*    eidx   = (int*)p;     p += (size_t)NE * 4;
    float*  biasH  = (float*)p;   p += HID * 4;
    ushort* WlT    = (ushort*)p;  p += (size_t)HO * HID * 2;   // [1024][256]
    ushort* WrT    = (ushort*)p;  p += (size_t)HO * HID * 2;
    ushort* WeT    = (ushort*)p;  p += (size_t)HO * HID * 2;
    ushort* Wd1T   = (ushort*)p;  p += (size_t)HID * HO * 2;   // [256][1024]
    if ((size_t)(p - (char*)d_ws) > ws_size) return;  // clean fail, no OOB

    hipMemsetAsync(deg, 0, (size_t)NN * 4, stream);
    hipMemsetAsync(hid, 0, NODEH * 4, stream);

    node_enc_kernel<<<NN, 256, 0, stream>>>(x, W_ne, b_ne, h_bf);
    biasH_kernel<<<1, 256, 0, stream>>>(conv_bias, W_d1, b_d1, biasH);

    transpose_bf16_kernel<<<dim3(HID, HO / 256), 256, 0, stream>>>(W_l,  WlT,  HID, HO);
    transpose_bf16_kernel<<<dim3(HID, HO / 256), 256, 0, stream>>>(W_r,  WrT,  HID, HO);
    transpose_bf16_kernel<<<dim3(HID, HO / 256), 256, 0, stream>>>(W_e,  WeT,  HID, HO);
    transpose_bf16_kernel<<<dim3(HO, HID / 256), 256, 0, stream>>>(W_d1, Wd1T, HO,  HID);

    hist_kernel<<<(NE + 255) / 256, 256, 0, stream>>>(ei, deg);
    scan_kernel<<<1, 64, 0, stream>>>(deg, rowptr, cursor);
    scatter_kernel<<<(NE + 255) / 256, 256, 0, stream>>>(ei, cursor, eidx);

    const int gemmGrid = (NN + 63) / 64;     // 313
    const int edgeGrid = (NE + 63) / 64;     // 1563

    for (int hh = 0; hh < HEADS; hh++) {
        mfma_gemm_kernel<0><<<gemmGrid, 256, 0, stream>>>(
            h_bf, WlT + (size_t)hh * OUT * HID, HID, b_l + hh * OUT, xl_bf, NN);
        mfma_gemm_kernel<0><<<gemmGrid, 256, 0, stream>>>(
            h_bf, WrT + (size_t)hh * OUT * HID, HID, b_r + hh * OUT, xr_bf, NN);

        edge_mfma_logits_kernel<<<edgeGrid, 256, 0, stream>>>(
            edge_attr, W_ee, b_ee, WeT + (size_t)hh * OUT * HID,
            b_e + hh * OUT, att + hh * OUT, xl_bf, xr_bf, ei, lbuf4, hh);

        softmax_agg_kernel<<<(NN + 3) / 4, 256, 0, stream>>>(
            lbuf4, rowptr, eidx, ei, xl_bf, agg_bf, hh);

        mfma_gemm_kernel<1><<<gemmGrid, 256, 0, stream>>>(
            agg_bf, Wd1T + hh * OUT, HO, nullptr, hid, NN);
    }

    hid_relu_kernel<<<(NN * HID + 255) / 256, 256, 0, stream>>>(hid, biasH);
    final_kernel<<<(NN * 6 + 255) / 256, 256, 0, stream>>>(hid, W_d2, b_d2, out);
}

// Round 7
// 863.246 us; speedup vs baseline: 2.5034x; 1.1497x over previous
//
#include <hip/hip_runtime.h>
#include <hip/hip_bf16.h>

#define NN 20000
#define NE 100000
#define HID 256
#define HO 1024   // HEADS*OUT
#define HEADS 4
#define OUT 256

typedef __attribute__((ext_vector_type(8))) short bf16x8;
typedef __attribute__((ext_vector_type(4))) float f32x4;

__device__ inline ushort f2bf(float f) {
    union { float f; unsigned u; } v; v.f = f;
    unsigned r = v.u + 0x7FFFu + ((v.u >> 16) & 1u);  // RNE
    return (ushort)(r >> 16);
}
__device__ inline float bf2f(ushort b) {
    union { unsigned u; float f; } v; v.u = ((unsigned)b) << 16;
    return v.f;
}

// ---------------------------------------------------------------------------
// K1: h_bf = bf16(relu(x @ W_ne + b_ne))   x:[N,7] W:[7,256]
__global__ __launch_bounds__(256) void node_enc_kernel(
    const float* __restrict__ x, const float* __restrict__ W,
    const float* __restrict__ b, ushort* __restrict__ h)
{
    int n = blockIdx.x;
    int c = threadIdx.x;
    __shared__ float xs[8];
    if (threadIdx.x < 7) xs[threadIdx.x] = x[n * 7 + threadIdx.x];
    __syncthreads();
    float acc = b[c];
#pragma unroll
    for (int k = 0; k < 7; k++) acc += xs[k] * W[k * HID + c];
    h[(size_t)n * HID + c] = f2bf(fmaxf(acc, 0.f));
}

// ---------------------------------------------------------------------------
// WT[n][k] = bf16(W[k][n])   W:[K,N]  grid=dim3(K, N/256)
__global__ __launch_bounds__(256) void transpose_bf16_kernel(
    const float* __restrict__ W, ushort* __restrict__ WT, int K, int N)
{
    int k = blockIdx.x;
    int n = blockIdx.y * 256 + threadIdx.x;
    WT[(size_t)n * K + k] = f2bf(W[(size_t)k * N + n]);
}

// ---------------------------------------------------------------------------
// biasH[c] = b_d1[c] + sum_k conv_bias[k] * W_d1[k,c]
__global__ __launch_bounds__(256) void biasH_kernel(
    const float* __restrict__ conv_bias, const float* __restrict__ W_d1,
    const float* __restrict__ b_d1, float* __restrict__ biasH)
{
    int c = threadIdx.x;
    float acc = b_d1[c];
    for (int k = 0; k < HO; k++) acc += conv_bias[k] * W_d1[(size_t)k * HID + c];
    biasH[c] = acc;
}

// ---------------------------------------------------------------------------
// CSR build
__global__ __launch_bounds__(256) void hist_kernel(
    const int* __restrict__ ei, int* __restrict__ deg)
{
    int e = blockIdx.x * blockDim.x + threadIdx.x;
    if (e >= NE) return;
    atomicAdd(&deg[ei[NE + e]], 1);
}

__global__ __launch_bounds__(64) void scan_kernel(
    const int* __restrict__ deg, int* __restrict__ rowptr, int* __restrict__ cursor)
{
    const int CH = 313;   // 64*313 = 20032 >= 20000
    int t = threadIdx.x;
    int start = t * CH, end = min(NN, start + CH);
    int local = 0;
    for (int i = start; i < end; i++) local += deg[i];
    int incl = local;
#pragma unroll
    for (int off = 1; off < 64; off <<= 1) {
        int v = __shfl_up(incl, off);
        if (t >= off) incl += v;
    }
    int run = incl - local;
    for (int i = start; i < end; i++) {
        rowptr[i] = run;
        cursor[i] = run;
        run += deg[i];
    }
    if (t == 63) rowptr[NN] = run;
}

__global__ __launch_bounds__(256) void scatter_kernel(
    const int* __restrict__ ei, int* __restrict__ cursor, int* __restrict__ eidx)
{
    int e = blockIdx.x * blockDim.x + threadIdx.x;
    if (e >= NE) return;
    int d = ei[NE + e];
    int pos = atomicAdd(&cursor[d], 1);
    eidx[pos] = e;
}

// ---------------------------------------------------------------------------
// MFMA GEMM: C[M,256] = A[M,256] @ BT[256 cols][256 k]^T  (BT row n = col n of B)
// A tile staged in LDS (coalesced). MODE 0: C bf16 = res + bias. MODE 1: C f32 +=.
template <int MODE>
__global__ __launch_bounds__(256) void mfma_gemm_kernel(
    const ushort* __restrict__ A, const ushort* __restrict__ BT, int ldBT,
    const float* __restrict__ bias, void* __restrict__ Cv, int M)
{
    __shared__ __align__(16) ushort As[64][264];
    int t = threadIdx.x, w = t >> 6, lane = t & 63;
    int l15 = lane & 15, l4 = lane >> 4;
    int row0 = blockIdx.x * 64;
    {   // stage A tile: thread t -> row t>>2, 128B chunk (t&3)
        int r = t >> 2, c0 = (t & 3) * 64;
        int row = row0 + r;
        if (row < M) {
            const ushort* src = &A[(size_t)row * 256 + c0];
#pragma unroll
            for (int c = 0; c < 8; c++)
                *(bf16x8*)&As[r][c0 + c * 8] = *(const bf16x8*)&src[c * 8];
        } else {
            bf16x8 z = (bf16x8){0, 0, 0, 0, 0, 0, 0, 0};
#pragma unroll
            for (int c = 0; c < 8; c++) *(bf16x8*)&As[r][c0 + c * 8] = z;
        }
    }
    __syncthreads();
    f32x4 acc[4][4] = {};
    for (int k0 = 0; k0 < 256; k0 += 32) {
        bf16x8 a[4], b[4];
#pragma unroll
        for (int rt = 0; rt < 4; rt++)
            a[rt] = *(const bf16x8*)&As[rt * 16 + l15][k0 + l4 * 8];
#pragma unroll
        for (int ct = 0; ct < 4; ct++) {
            int n = w * 64 + ct * 16 + l15;
            b[ct] = *(const bf16x8*)&BT[(size_t)n * ldBT + k0 + l4 * 8];
        }
#pragma unroll
        for (int rt = 0; rt < 4; rt++)
#pragma unroll
            for (int ct = 0; ct < 4; ct++)
                acc[rt][ct] = __builtin_amdgcn_mfma_f32_16x16x32_bf16(
                    a[rt], b[ct], acc[rt][ct], 0, 0, 0);
    }
    if constexpr (MODE == 0) {
        ushort* C = (ushort*)Cv;
        float bv[4];
#pragma unroll
        for (int ct = 0; ct < 4; ct++) bv[ct] = bias[w * 64 + ct * 16 + l15];
#pragma unroll
        for (int rt = 0; rt < 4; rt++)
#pragma unroll
            for (int ct = 0; ct < 4; ct++)
#pragma unroll
                for (int r = 0; r < 4; r++) {
                    int row = row0 + rt * 16 + l4 * 4 + r;
                    if (row < M)
                        C[(size_t)row * 256 + w * 64 + ct * 16 + l15] =
                            f2bf(acc[rt][ct][r] + bv[ct]);
                }
    } else {
        float* C = (float*)Cv;
#pragma unroll
        for (int rt = 0; rt < 4; rt++)
#pragma unroll
            for (int ct = 0; ct < 4; ct++)
#pragma unroll
                for (int r = 0; r < 4; r++) {
                    int row = row0 + rt * 16 + l4 * 4 + r;
                    if (row < M)
                        C[(size_t)row * 256 + w * 64 + ct * 16 + l15] += acc[rt][ct][r];
                }
    }
}

// ---------------------------------------------------------------------------
// Fused edge kernel (per head): 32 edges/block, 4 waves — sized for occupancy
// (Guideline 1): acc[2][4]=32 VGPR, LDS ~18.6KB -> target 5+ blocks/CU.
// A: e_enc [32,256] bf16 -> LDS (K=7 recompute).
// B: e_h via MFMA vs WeT head slice.
// C: per 16-edge group, stage xl[src]/xr[dst] rows into LDS (coalesced 16B),
//    then logit = sum_c lrelu(e_h + b_e + xl + xr) * att from LDS.
// D: 16-lane shfl + cross-wave reduce -> lbuf4[e*4+h].
#define EPB 32
__global__ __launch_bounds__(256) void edge_mfma_logits_kernel(
    const float* __restrict__ edge_attr, const float* __restrict__ W_ee,
    const float* __restrict__ b_ee, const ushort* __restrict__ WeTh,
    const float* __restrict__ b_e_h, const float* __restrict__ att_h,
    const ushort* __restrict__ xl, const ushort* __restrict__ xr,
    const int* __restrict__ ei, float* __restrict__ lbuf4, int h)
{
    __shared__ __align__(16) ushort As[EPB][264];   // 16.9 KB; reused as XL/XR
    __shared__ float ea[EPB * 7];
    __shared__ int sArr[EPB], dArr[EPB];
    __shared__ float red[4][EPB];
    ushort (*XL)[264] = As;        // rows 0..15
    ushort (*XR)[264] = As + 16;   // rows 16..31
    int e0 = blockIdx.x * EPB;     // NE % EPB == 0 -> no partial blocks
    int t = threadIdx.x, w = t >> 6, lane = t & 63;
    int l15 = lane & 15, l4 = lane >> 4;

    if (t < EPB * 7) ea[t] = edge_attr[(size_t)e0 * 7 + t];
    if (t < EPB) {
        sArr[t] = ei[e0 + t];
        dArr[t] = ei[NE + e0 + t];
    }
    float w7[7];
#pragma unroll
    for (int k = 0; k < 7; k++) w7[k] = W_ee[k * HID + t];
    float bee = b_ee[t];
    __syncthreads();

    // ---- phase A: e_enc ----
#pragma unroll 4
    for (int r = 0; r < EPB; r++) {
        float acc = bee;
#pragma unroll
        for (int k = 0; k < 7; k++) acc += w7[k] * ea[r * 7 + k];
        As[r][t] = f2bf(fmaxf(acc, 0.f));
    }
    __syncthreads();

    // ---- phase B: MFMA ----
    f32x4 acc[2][4] = {};
    for (int k0 = 0; k0 < 256; k0 += 32) {
        bf16x8 a[2], b[4];
#pragma unroll
        for (int rt = 0; rt < 2; rt++)
            a[rt] = *(const bf16x8*)&As[rt * 16 + l15][k0 + l4 * 8];
#pragma unroll
        for (int ct = 0; ct < 4; ct++) {
            int n = w * 64 + ct * 16 + l15;
            b[ct] = *(const bf16x8*)&WeTh[(size_t)n * 256 + k0 + l4 * 8];
        }
#pragma unroll
        for (int rt = 0; rt < 2; rt++)
#pragma unroll
            for (int ct = 0; ct < 4; ct++)
                acc[rt][ct] = __builtin_amdgcn_mfma_f32_16x16x32_bf16(
                    a[rt], b[ct], acc[rt][ct], 0, 0, 0);
    }

    float bev[4], atv[4];
#pragma unroll
    for (int ct = 0; ct < 4; ct++) {
        int col = w * 64 + ct * 16 + l15;
        bev[ct] = b_e_h[col];
        atv[ct] = att_h[col];
    }
    __syncthreads();   // e_enc consumed; reuse As as XL/XR

    // ---- phase C: stage gathers per 16-edge group, compute logits ----
    int sli = t >> 4;           // staging row 0..15
    int sch = (t & 15) * 16;    // staging col chunk (32B)
    float lp[2][4];
#pragma unroll
    for (int rt = 0; rt < 2; rt++) {
        {
            int sRow = sArr[rt * 16 + sli], dRow = dArr[rt * 16 + sli];
            const ushort* ps = &xl[(size_t)sRow * 256 + sch];
            const ushort* pd = &xr[(size_t)dRow * 256 + sch];
            bf16x8 v0 = *(const bf16x8*)ps;
            bf16x8 v1 = *(const bf16x8*)(ps + 8);
            bf16x8 v2 = *(const bf16x8*)pd;
            bf16x8 v3 = *(const bf16x8*)(pd + 8);
            *(bf16x8*)&XL[sli][sch]     = v0;
            *(bf16x8*)&XL[sli][sch + 8] = v1;
            *(bf16x8*)&XR[sli][sch]     = v2;
            *(bf16x8*)&XR[sli][sch + 8] = v3;
        }
        __syncthreads();
#pragma unroll
        for (int r = 0; r < 4; r++) {
            int li = l4 * 4 + r;
            float p = 0.f;
#pragma unroll
            for (int ct = 0; ct < 4; ct++) {
                int col = w * 64 + ct * 16 + l15;
                float z = acc[rt][ct][r] + bev[ct] +
                          bf2f(XL[li][col]) + bf2f(XR[li][col]);
                z = (z > 0.f) ? z : 0.2f * z;
                p += z * atv[ct];
            }
            lp[rt][r] = p;
        }
        __syncthreads();
    }

#pragma unroll
    for (int off = 1; off < 16; off <<= 1)
#pragma unroll
        for (int rt = 0; rt < 2; rt++)
#pragma unroll
            for (int r = 0; r < 4; r++)
                lp[rt][r] += __shfl_xor(lp[rt][r], off);
    if (l15 == 0)
#pragma unroll
        for (int rt = 0; rt < 2; rt++)
#pragma unroll
            for (int r = 0; r < 4; r++)
                red[w][rt * 16 + l4 * 4 + r] = lp[rt][r];
    __syncthreads();
    if (t < EPB) {
        float v = red[0][t] + red[1][t] + red[2][t] + red[3][t];
        lbuf4[(size_t)(e0 + t) * 4 + h] = v;
    }
}

// ---------------------------------------------------------------------------
// Fused segment softmax + aggregation (per head). One wave per dst node.
__global__ __launch_bounds__(256) void softmax_agg_kernel(
    const float* __restrict__ lbuf4, const int* __restrict__ rowptr,
    const int* __restrict__ eidx, const int* __restrict__ ei,
    const ushort* __restrict__ xl, ushort* __restrict__ agg, int h)
{
    int wv = threadIdx.x >> 6, lane = threadIdx.x & 63;
    int n = blockIdx.x * 4 + wv;
    if (n >= NN) return;
    int r0 = rowptr[n], r1 = rowptr[n + 1];
    float m = -3.4e38f;
    for (int j = r0; j < r1; j++)
        m = fmaxf(m, lbuf4[(size_t)eidx[j] * 4 + h]);
    float denom = 0.f;
    for (int j = r0; j < r1; j++)
        denom += __expf(lbuf4[(size_t)eidx[j] * 4 + h] - m);
    float rd = (denom > 0.f) ? 1.f / denom : 0.f;
    float a0 = 0.f, a1 = 0.f, a2 = 0.f, a3 = 0.f;
    for (int j = r0; j < r1; j++) {
        int e = eidx[j];
        int s = ei[e];
        float alpha = __expf(lbuf4[(size_t)e * 4 + h] - m) * rd;
        ushort4 xv = *(const ushort4*)&xl[(size_t)s * 256 + lane * 4];
        a0 += alpha * bf2f(xv.x); a1 += alpha * bf2f(xv.y);
        a2 += alpha * bf2f(xv.z); a3 += alpha * bf2f(xv.w);
    }
    ushort4 o;
    o.x = f2bf(a0); o.y = f2bf(a1); o.z = f2bf(a2); o.w = f2bf(a3);
    *(ushort4*)&agg[(size_t)n * 256 + lane * 4] = o;
}

// ---------------------------------------------------------------------------
// hid = relu(hid + biasH)
__global__ __launch_bounds__(256) void hid_relu_kernel(
    float* __restrict__ hid, const float* __restrict__ biasH)
{
    int g = blockIdx.x * blockDim.x + threadIdx.x;
    if (g >= NN * HID) return;
    hid[g] = fmaxf(hid[g] + biasH[g & (HID - 1)], 0.f);
}

// ---------------------------------------------------------------------------
// out = sigmoid(hid @ W_d2 + b_d2)
__global__ __launch_bounds__(256) void final_kernel(
    const float* __restrict__ hid, const float* __restrict__ W_d2,
    const float* __restrict__ b_d2, float* __restrict__ out)
{
    int g = blockIdx.x * blockDim.x + threadIdx.x;
    if (g >= NN * 6) return;
    int n = g / 6, j = g % 6;
    float acc = b_d2[j];
    const float4* hp = reinterpret_cast<const float4*>(&hid[(size_t)n * HID]);
#pragma unroll 4
    for (int k4 = 0; k4 < HID / 4; k4++) {
        float4 hv = hp[k4];
        int k = k4 * 4;
        acc += hv.x * W_d2[(k + 0) * 6 + j] + hv.y * W_d2[(k + 1) * 6 + j] +
               hv.z * W_d2[(k + 2) * 6 + j] + hv.w * W_d2[(k + 3) * 6 + j];
    }
    out[g] = 1.f / (1.f + __expf(-acc));
}

// ---------------------------------------------------------------------------
extern "C" void kernel_launch(void* const* d_in, const int* in_sizes, int n_in,
                              void* d_out, int out_size, void* d_ws, size_t ws_size,
                              hipStream_t stream)
{
    const float* x         = (const float*)d_in[0];
    const float* edge_attr = (const float*)d_in[1];
    const float* W_ne = (const float*)d_in[2];  const float* b_ne = (const float*)d_in[3];
    const float* W_ee = (const float*)d_in[4];  const float* b_ee = (const float*)d_in[5];
    const float* W_l  = (const float*)d_in[6];  const float* b_l  = (const float*)d_in[7];
    const float* W_r  = (const float*)d_in[8];  const float* b_r  = (const float*)d_in[9];
    const float* W_e  = (const float*)d_in[10]; const float* b_e  = (const float*)d_in[11];
    const float* att  = (const float*)d_in[12];
    const float* conv_bias = (const float*)d_in[13];
    const float* W_d1 = (const float*)d_in[14]; const float* b_d1 = (const float*)d_in[15];
    const float* W_d2 = (const float*)d_in[16]; const float* b_d2 = (const float*)d_in[17];
    const int*   ei   = (const int*)d_in[18];
    float* out = (float*)d_out;

    const size_t NODEH = (size_t)NN * HID;   // 5.12M
    char* p = (char*)d_ws;
    ushort* h_bf   = (ushort*)p;  p += NODEH * 2;
    ushort* xl_bf  = (ushort*)p;  p += NODEH * 2;
    ushort* xr_bf  = (ushort*)p;  p += NODEH * 2;
    ushort* agg_bf = (ushort*)p;  p += NODEH * 2;
    float*  hid    = (float*)p;   p += NODEH * 4;
    float*  lbuf4  = (float*)p;   p += (size_t)NE * HEADS * 4;
    int*    deg    = (int*)p;     p += (size_t)NN * 4;
    int*    rowptr = (int*)p;     p += (size_t)(NN + 1) * 4;
    int*    cursor = (int*)p;     p += (size_t)NN * 4;
    int*    eidx   = (int*)p;     p += (size_t)NE * 4;
    float*  biasH  = (float*)p;   p += HID * 4;
    ushort* WlT    = (ushort*)p;  p += (size_t)HO * HID * 2;   // [1024][256]
    ushort* WrT    = (ushort*)p;  p += (size_t)HO * HID * 2;
    ushort* WeT    = (ushort*)p;  p += (size_t)HO * HID * 2;
    ushort* Wd1T   = (ushort*)p;  p += (size_t)HID * HO * 2;   // [256][1024]
    if ((size_t)(p - (char*)d_ws) > ws_size) return;  // clean fail, no OOB

    hipMemsetAsync(deg, 0, (size_t)NN * 4, stream);
    hipMemsetAsync(hid, 0, NODEH * 4, stream);

    node_enc_kernel<<<NN, 256, 0, stream>>>(x, W_ne, b_ne, h_bf);
    biasH_kernel<<<1, 256, 0, stream>>>(conv_bias, W_d1, b_d1, biasH);

    transpose_bf16_kernel<<<dim3(HID, HO / 256), 256, 0, stream>>>(W_l,  WlT,  HID, HO);
    transpose_bf16_kernel<<<dim3(HID, HO / 256), 256, 0, stream>>>(W_r,  WrT,  HID, HO);
    transpose_bf16_kernel<<<dim3(HID, HO / 256), 256, 0, stream>>>(W_e,  WeT,  HID, HO);
    transpose_bf16_kernel<<<dim3(HO, HID / 256), 256, 0, stream>>>(W_d1, Wd1T, HO,  HID);

    hist_kernel<<<(NE + 255) / 256, 256, 0, stream>>>(ei, deg);
    scan_kernel<<<1, 64, 0, stream>>>(deg, rowptr, cursor);
    scatter_kernel<<<(NE + 255) / 256, 256, 0, stream>>>(ei, cursor, eidx);

    const int gemmGrid = (NN + 63) / 64;     // 313
    const int edgeGrid = NE / EPB;           // 3125

    for (int hh = 0; hh < HEADS; hh++) {
        mfma_gemm_kernel<0><<<gemmGrid, 256, 0, stream>>>(
            h_bf, WlT + (size_t)hh * OUT * HID, HID, b_l + hh * OUT, xl_bf, NN);
        mfma_gemm_kernel<0><<<gemmGrid, 256, 0, stream>>>(
            h_bf, WrT + (size_t)hh * OUT * HID, HID, b_r + hh * OUT, xr_bf, NN);

        edge_mfma_logits_kernel<<<edgeGrid, 256, 0, stream>>>(
            edge_attr, W_ee, b_ee, WeT + (size_t)hh * OUT * HID,
            b_e + hh * OUT, att + hh * OUT, xl_bf, xr_bf, ei, lbuf4, hh);

        softmax_agg_kernel<<<(NN + 3) / 4, 256, 0, stream>>>(
            lbuf4, rowptr, eidx, ei, xl_bf, agg_bf, hh);

        mfma_gemm_kernel<1><<<gemmGrid, 256, 0, stream>>>(
            agg_bf, Wd1T + hh * OUT, HO, nullptr, hid, NN);
    }

    hid_relu_kernel<<<(NN * HID + 255) / 256, 256, 0, stream>>>(hid, biasH);
    final_kernel<<<(NN * 6 + 255) / 256, 256, 0, stream>>>(hid, W_d2, b_d2, out);
}

// Round 8
// 803.045 us; speedup vs baseline: 2.6911x; 1.0750x over previous
//
#include <hip/hip_runtime.h>
#include <hip/hip_bf16.h>

#define NN 20000
#define NE 100000
#define HID 256
#define HO 1024   // HEADS*OUT
#define HEADS 4
#define OUT 256

typedef __attribute__((ext_vector_type(8))) short bf16x8;
typedef __attribute__((ext_vector_type(4))) float f32x4;

__device__ inline ushort f2bf(float f) {
    union { float f; unsigned u; } v; v.f = f;
    unsigned r = v.u + 0x7FFFu + ((v.u >> 16) & 1u);  // RNE
    return (ushort)(r >> 16);
}
__device__ inline float bf2f(ushort b) {
    union { unsigned u; float f; } v; v.u = ((unsigned)b) << 16;
    return v.f;
}

// ---------------------------------------------------------------------------
// K1: h_bf = bf16(relu(x @ W_ne + b_ne))   x:[N,7] W:[7,256]
__global__ __launch_bounds__(256) void node_enc_kernel(
    const float* __restrict__ x, const float* __restrict__ W,
    const float* __restrict__ b, ushort* __restrict__ h)
{
    int n = blockIdx.x;
    int c = threadIdx.x;
    __shared__ float xs[8];
    if (threadIdx.x < 7) xs[threadIdx.x] = x[n * 7 + threadIdx.x];
    __syncthreads();
    float acc = b[c];
#pragma unroll
    for (int k = 0; k < 7; k++) acc += xs[k] * W[k * HID + c];
    h[(size_t)n * HID + c] = f2bf(fmaxf(acc, 0.f));
}

// ---------------------------------------------------------------------------
// WT[n][k] = bf16(W[k][n])   W:[K,N]  grid=dim3(K, N/256)
__global__ __launch_bounds__(256) void transpose_bf16_kernel(
    const float* __restrict__ W, ushort* __restrict__ WT, int K, int N)
{
    int k = blockIdx.x;
    int n = blockIdx.y * 256 + threadIdx.x;
    WT[(size_t)n * K + k] = f2bf(W[(size_t)k * N + n]);
}

// ---------------------------------------------------------------------------
// biasH[c] = b_d1[c] + sum_k conv_bias[k] * W_d1[k,c]
__global__ __launch_bounds__(256) void biasH_kernel(
    const float* __restrict__ conv_bias, const float* __restrict__ W_d1,
    const float* __restrict__ b_d1, float* __restrict__ biasH)
{
    int c = threadIdx.x;
    float acc = b_d1[c];
    for (int k = 0; k < HO; k++) acc += conv_bias[k] * W_d1[(size_t)k * HID + c];
    biasH[c] = acc;
}

// ---------------------------------------------------------------------------
// CSR build
__global__ __launch_bounds__(256) void hist_kernel(
    const int* __restrict__ ei, int* __restrict__ deg)
{
    int e = blockIdx.x * blockDim.x + threadIdx.x;
    if (e >= NE) return;
    atomicAdd(&deg[ei[NE + e]], 1);
}

// 1 block x 1024 threads: thread t owns nodes [t*20, t*20+20) in registers;
// wave shfl-scan + cross-wave LDS scan of 16 wave totals.
__global__ __launch_bounds__(1024) void scan_kernel(
    const int* __restrict__ deg, int* __restrict__ rowptr, int* __restrict__ cursor)
{
    const int CH = 20;   // 1024*20 = 20480 >= 20000
    int t = threadIdx.x;
    int start = t * CH;
    int d[CH];
    int local = 0;
#pragma unroll
    for (int i = 0; i < CH; i++) {
        int idx = start + i;
        d[i] = (idx < NN) ? deg[idx] : 0;
        local += d[i];
    }
    int incl = local;
#pragma unroll
    for (int off = 1; off < 64; off <<= 1) {
        int v = __shfl_up(incl, off);
        if ((t & 63) >= off) incl += v;
    }
    __shared__ int waveTot[16];
    int wv = t >> 6;
    if ((t & 63) == 63) waveTot[wv] = incl;
    __syncthreads();
    if (t < 16) {
        int v = waveTot[t];
        int s = v;
#pragma unroll
        for (int off = 1; off < 16; off <<= 1) {
            int u = __shfl_up(s, off);
            if (t >= off) s += u;
        }
        waveTot[t] = s - v;   // exclusive prefix of wave totals
    }
    __syncthreads();
    int run = (incl - local) + waveTot[wv];   // exclusive prefix for this thread
#pragma unroll
    for (int i = 0; i < CH; i++) {
        int idx = start + i;
        if (idx < NN) { rowptr[idx] = run; cursor[idx] = run; }
        run += d[i];
    }
    if (t == 1023) rowptr[NN] = run;
}

__global__ __launch_bounds__(256) void scatter_kernel(
    const int* __restrict__ ei, int* __restrict__ cursor, int* __restrict__ eidx)
{
    int e = blockIdx.x * blockDim.x + threadIdx.x;
    if (e >= NE) return;
    int d = ei[NE + e];
    int pos = atomicAdd(&cursor[d], 1);
    eidx[pos] = e;
}

// ---------------------------------------------------------------------------
// MFMA GEMM: C[M,256] = A[M,256] @ BT[256 cols][256 k]^T  (BT row n = col n of B)
// A tile staged in LDS (coalesced). MODE 0: C bf16 = res + bias. MODE 1: C f32 +=.
template <int MODE>
__global__ __launch_bounds__(256) void mfma_gemm_kernel(
    const ushort* __restrict__ A, const ushort* __restrict__ BT, int ldBT,
    const float* __restrict__ bias, void* __restrict__ Cv, int M)
{
    __shared__ __align__(16) ushort As[64][264];
    int t = threadIdx.x, w = t >> 6, lane = t & 63;
    int l15 = lane & 15, l4 = lane >> 4;
    int row0 = blockIdx.x * 64;
    {   // stage A tile: thread t -> row t>>2, 128B chunk (t&3)
        int r = t >> 2, c0 = (t & 3) * 64;
        int row = row0 + r;
        if (row < M) {
            const ushort* src = &A[(size_t)row * 256 + c0];
#pragma unroll
            for (int c = 0; c < 8; c++)
                *(bf16x8*)&As[r][c0 + c * 8] = *(const bf16x8*)&src[c * 8];
        } else {
            bf16x8 z = (bf16x8){0, 0, 0, 0, 0, 0, 0, 0};
#pragma unroll
            for (int c = 0; c < 8; c++) *(bf16x8*)&As[r][c0 + c * 8] = z;
        }
    }
    __syncthreads();
    f32x4 acc[4][4] = {};
    for (int k0 = 0; k0 < 256; k0 += 32) {
        bf16x8 a[4], b[4];
#pragma unroll
        for (int rt = 0; rt < 4; rt++)
            a[rt] = *(const bf16x8*)&As[rt * 16 + l15][k0 + l4 * 8];
#pragma unroll
        for (int ct = 0; ct < 4; ct++) {
            int n = w * 64 + ct * 16 + l15;
            b[ct] = *(const bf16x8*)&BT[(size_t)n * ldBT + k0 + l4 * 8];
        }
#pragma unroll
        for (int rt = 0; rt < 4; rt++)
#pragma unroll
            for (int ct = 0; ct < 4; ct++)
                acc[rt][ct] = __builtin_amdgcn_mfma_f32_16x16x32_bf16(
                    a[rt], b[ct], acc[rt][ct], 0, 0, 0);
    }
    if constexpr (MODE == 0) {
        ushort* C = (ushort*)Cv;
        float bv[4];
#pragma unroll
        for (int ct = 0; ct < 4; ct++) bv[ct] = bias[w * 64 + ct * 16 + l15];
#pragma unroll
        for (int rt = 0; rt < 4; rt++)
#pragma unroll
            for (int ct = 0; ct < 4; ct++)
#pragma unroll
                for (int r = 0; r < 4; r++) {
                    int row = row0 + rt * 16 + l4 * 4 + r;
                    if (row < M)
                        C[(size_t)row * 256 + w * 64 + ct * 16 + l15] =
                            f2bf(acc[rt][ct][r] + bv[ct]);
                }
    } else {
        float* C = (float*)Cv;
#pragma unroll
        for (int rt = 0; rt < 4; rt++)
#pragma unroll
            for (int ct = 0; ct < 4; ct++)
#pragma unroll
                for (int r = 0; r < 4; r++) {
                    int row = row0 + rt * 16 + l4 * 4 + r;
                    if (row < M)
                        C[(size_t)row * 256 + w * 64 + ct * 16 + l15] += acc[rt][ct][r];
                }
    }
}

// ---------------------------------------------------------------------------
// Fused edge kernel (per head): 32 edges/block, 4 waves — sized for occupancy.
#define EPB 32
__global__ __launch_bounds__(256) void edge_mfma_logits_kernel(
    const float* __restrict__ edge_attr, const float* __restrict__ W_ee,
    const float* __restrict__ b_ee, const ushort* __restrict__ WeTh,
    const float* __restrict__ b_e_h, const float* __restrict__ att_h,
    const ushort* __restrict__ xl, const ushort* __restrict__ xr,
    const int* __restrict__ ei, float* __restrict__ lbuf4, int h)
{
    __shared__ __align__(16) ushort As[EPB][264];   // 16.9 KB; reused as XL/XR
    __shared__ float ea[EPB * 7];
    __shared__ int sArr[EPB], dArr[EPB];
    __shared__ float red[4][EPB];
    ushort (*XL)[264] = As;        // rows 0..15
    ushort (*XR)[264] = As + 16;   // rows 16..31
    int e0 = blockIdx.x * EPB;     // NE % EPB == 0 -> no partial blocks
    int t = threadIdx.x, w = t >> 6, lane = t & 63;
    int l15 = lane & 15, l4 = lane >> 4;

    if (t < EPB * 7) ea[t] = edge_attr[(size_t)e0 * 7 + t];
    if (t < EPB) {
        sArr[t] = ei[e0 + t];
        dArr[t] = ei[NE + e0 + t];
    }
    float w7[7];
#pragma unroll
    for (int k = 0; k < 7; k++) w7[k] = W_ee[k * HID + t];
    float bee = b_ee[t];
    __syncthreads();

    // ---- phase A: e_enc ----
#pragma unroll 4
    for (int r = 0; r < EPB; r++) {
        float acc = bee;
#pragma unroll
        for (int k = 0; k < 7; k++) acc += w7[k] * ea[r * 7 + k];
        As[r][t] = f2bf(fmaxf(acc, 0.f));
    }
    __syncthreads();

    // ---- phase B: MFMA ----
    f32x4 acc[2][4] = {};
    for (int k0 = 0; k0 < 256; k0 += 32) {
        bf16x8 a[2], b[4];
#pragma unroll
        for (int rt = 0; rt < 2; rt++)
            a[rt] = *(const bf16x8*)&As[rt * 16 + l15][k0 + l4 * 8];
#pragma unroll
        for (int ct = 0; ct < 4; ct++) {
            int n = w * 64 + ct * 16 + l15;
            b[ct] = *(const bf16x8*)&WeTh[(size_t)n * 256 + k0 + l4 * 8];
        }
#pragma unroll
        for (int rt = 0; rt < 2; rt++)
#pragma unroll
            for (int ct = 0; ct < 4; ct++)
                acc[rt][ct] = __builtin_amdgcn_mfma_f32_16x16x32_bf16(
                    a[rt], b[ct], acc[rt][ct], 0, 0, 0);
    }

    float bev[4], atv[4];
#pragma unroll
    for (int ct = 0; ct < 4; ct++) {
        int col = w * 64 + ct * 16 + l15;
        bev[ct] = b_e_h[col];
        atv[ct] = att_h[col];
    }
    __syncthreads();   // e_enc consumed; reuse As as XL/XR

    // ---- phase C: stage gathers per 16-edge group, compute logits ----
    int sli = t >> 4;           // staging row 0..15
    int sch = (t & 15) * 16;    // staging col chunk (32B)
    float lp[2][4];
#pragma unroll
    for (int rt = 0; rt < 2; rt++) {
        {
            int sRow = sArr[rt * 16 + sli], dRow = dArr[rt * 16 + sli];
            const ushort* ps = &xl[(size_t)sRow * 256 + sch];
            const ushort* pd = &xr[(size_t)dRow * 256 + sch];
            bf16x8 v0 = *(const bf16x8*)ps;
            bf16x8 v1 = *(const bf16x8*)(ps + 8);
            bf16x8 v2 = *(const bf16x8*)pd;
            bf16x8 v3 = *(const bf16x8*)(pd + 8);
            *(bf16x8*)&XL[sli][sch]     = v0;
            *(bf16x8*)&XL[sli][sch + 8] = v1;
            *(bf16x8*)&XR[sli][sch]     = v2;
            *(bf16x8*)&XR[sli][sch + 8] = v3;
        }
        __syncthreads();
#pragma unroll
        for (int r = 0; r < 4; r++) {
            int li = l4 * 4 + r;
            float p = 0.f;
#pragma unroll
            for (int ct = 0; ct < 4; ct++) {
                int col = w * 64 + ct * 16 + l15;
                float z = acc[rt][ct][r] + bev[ct] +
                          bf2f(XL[li][col]) + bf2f(XR[li][col]);
                z = (z > 0.f) ? z : 0.2f * z;
                p += z * atv[ct];
            }
            lp[rt][r] = p;
        }
        __syncthreads();
    }

#pragma unroll
    for (int off = 1; off < 16; off <<= 1)
#pragma unroll
        for (int rt = 0; rt < 2; rt++)
#pragma unroll
            for (int r = 0; r < 4; r++)
                lp[rt][r] += __shfl_xor(lp[rt][r], off);
    if (l15 == 0)
#pragma unroll
        for (int rt = 0; rt < 2; rt++)
#pragma unroll
            for (int r = 0; r < 4; r++)
                red[w][rt * 16 + l4 * 4 + r] = lp[rt][r];
    __syncthreads();
    if (t < EPB) {
        float v = red[0][t] + red[1][t] + red[2][t] + red[3][t];
        lbuf4[(size_t)(e0 + t) * 4 + h] = v;
    }
}

// ---------------------------------------------------------------------------
// Fused segment softmax + aggregation (per head). One wave per dst node.
__global__ __launch_bounds__(256) void softmax_agg_kernel(
    const float* __restrict__ lbuf4, const int* __restrict__ rowptr,
    const int* __restrict__ eidx, const int* __restrict__ ei,
    const ushort* __restrict__ xl, ushort* __restrict__ agg, int h)
{
    int wv = threadIdx.x >> 6, lane = threadIdx.x & 63;
    int n = blockIdx.x * 4 + wv;
    if (n >= NN) return;
    int r0 = rowptr[n], r1 = rowptr[n + 1];
    float m = -3.4e38f;
    for (int j = r0; j < r1; j++)
        m = fmaxf(m, lbuf4[(size_t)eidx[j] * 4 + h]);
    float denom = 0.f;
    for (int j = r0; j < r1; j++)
        denom += __expf(lbuf4[(size_t)eidx[j] * 4 + h] - m);
    float rd = (denom > 0.f) ? 1.f / denom : 0.f;
    float a0 = 0.f, a1 = 0.f, a2 = 0.f, a3 = 0.f;
    for (int j = r0; j < r1; j++) {
        int e = eidx[j];
        int s = ei[e];
        float alpha = __expf(lbuf4[(size_t)e * 4 + h] - m) * rd;
        ushort4 xv = *(const ushort4*)&xl[(size_t)s * 256 + lane * 4];
        a0 += alpha * bf2f(xv.x); a1 += alpha * bf2f(xv.y);
        a2 += alpha * bf2f(xv.z); a3 += alpha * bf2f(xv.w);
    }
    ushort4 o;
    o.x = f2bf(a0); o.y = f2bf(a1); o.z = f2bf(a2); o.w = f2bf(a3);
    *(ushort4*)&agg[(size_t)n * 256 + lane * 4] = o;
}

// ---------------------------------------------------------------------------
// hid = relu(hid + biasH)
__global__ __launch_bounds__(256) void hid_relu_kernel(
    float* __restrict__ hid, const float* __restrict__ biasH)
{
    int g = blockIdx.x * blockDim.x + threadIdx.x;
    if (g >= NN * HID) return;
    hid[g] = fmaxf(hid[g] + biasH[g & (HID - 1)], 0.f);
}

// ---------------------------------------------------------------------------
// out = sigmoid(hid @ W_d2 + b_d2)
__global__ __launch_bounds__(256) void final_kernel(
    const float* __restrict__ hid, const float* __restrict__ W_d2,
    const float* __restrict__ b_d2, float* __restrict__ out)
{
    int g = blockIdx.x * blockDim.x + threadIdx.x;
    if (g >= NN * 6) return;
    int n = g / 6, j = g % 6;
    float acc = b_d2[j];
    const float4* hp = reinterpret_cast<const float4*>(&hid[(size_t)n * HID]);
#pragma unroll 4
    for (int k4 = 0; k4 < HID / 4; k4++) {
        float4 hv = hp[k4];
        int k = k4 * 4;
        acc += hv.x * W_d2[(k + 0) * 6 + j] + hv.y * W_d2[(k + 1) * 6 + j] +
               hv.z * W_d2[(k + 2) * 6 + j] + hv.w * W_d2[(k + 3) * 6 + j];
    }
    out[g] = 1.f / (1.f + __expf(-acc));
}

// ---------------------------------------------------------------------------
extern "C" void kernel_launch(void* const* d_in, const int* in_sizes, int n_in,
                              void* d_out, int out_size, void* d_ws, size_t ws_size,
                              hipStream_t stream)
{
    const float* x         = (const float*)d_in[0];
    const float* edge_attr = (const float*)d_in[1];
    const float* W_ne = (const float*)d_in[2];  const float* b_ne = (const float*)d_in[3];
    const float* W_ee = (const float*)d_in[4];  const float* b_ee = (const float*)d_in[5];
    const float* W_l  = (const float*)d_in[6];  const float* b_l  = (const float*)d_in[7];
    const float* W_r  = (const float*)d_in[8];  const float* b_r  = (const float*)d_in[9];
    const float* W_e  = (const float*)d_in[10]; const float* b_e  = (const float*)d_in[11];
    const float* att  = (const float*)d_in[12];
    const float* conv_bias = (const float*)d_in[13];
    const float* W_d1 = (const float*)d_in[14]; const float* b_d1 = (const float*)d_in[15];
    const float* W_d2 = (const float*)d_in[16]; const float* b_d2 = (const float*)d_in[17];
    const int*   ei   = (const int*)d_in[18];
    float* out = (float*)d_out;

    const size_t NODEH = (size_t)NN * HID;   // 5.12M
    char* p = (char*)d_ws;
    ushort* h_bf   = (ushort*)p;  p += NODEH * 2;
    ushort* xl_bf  = (ushort*)p;  p += NODEH * 2;
    ushort* xr_bf  = (ushort*)p;  p += NODEH * 2;
    ushort* agg_bf = (ushort*)p;  p += NODEH * 2;
    float*  hid    = (float*)p;   p += NODEH * 4;
    float*  lbuf4  = (float*)p;   p += (size_t)NE * HEADS * 4;
    int*    deg    = (int*)p;     p += (size_t)NN * 4;
    int*    rowptr = (int*)p;     p += (size_t)(NN + 1) * 4;
    int*    cursor = (int*)p;     p += (size_t)NN * 4;
    int*    eidx   = (int*)p;     p += (size_t)NE * 4;
    float*  biasH  = (float*)p;   p += HID * 4;
    ushort* WlT    = (ushort*)p;  p += (size_t)HO * HID * 2;   // [1024][256]
    ushort* WrT    = (ushort*)p;  p += (size_t)HO * HID * 2;
    ushort* WeT    = (ushort*)p;  p += (size_t)HO * HID * 2;
    ushort* Wd1T   = (ushort*)p;  p += (size_t)HID * HO * 2;   // [256][1024]
    if ((size_t)(p - (char*)d_ws) > ws_size) return;  // clean fail, no OOB

    hipMemsetAsync(deg, 0, (size_t)NN * 4, stream);
    hipMemsetAsync(hid, 0, NODEH * 4, stream);

    node_enc_kernel<<<NN, 256, 0, stream>>>(x, W_ne, b_ne, h_bf);
    biasH_kernel<<<1, 256, 0, stream>>>(conv_bias, W_d1, b_d1, biasH);

    transpose_bf16_kernel<<<dim3(HID, HO / 256), 256, 0, stream>>>(W_l,  WlT,  HID, HO);
    transpose_bf16_kernel<<<dim3(HID, HO / 256), 256, 0, stream>>>(W_r,  WrT,  HID, HO);
    transpose_bf16_kernel<<<dim3(HID, HO / 256), 256, 0, stream>>>(W_e,  WeT,  HID, HO);
    transpose_bf16_kernel<<<dim3(HO, HID / 256), 256, 0, stream>>>(W_d1, Wd1T, HO,  HID);

    hist_kernel<<<(NE + 255) / 256, 256, 0, stream>>>(ei, deg);
    scan_kernel<<<1, 1024, 0, stream>>>(deg, rowptr, cursor);
    scatter_kernel<<<(NE + 255) / 256, 256, 0, stream>>>(ei, cursor, eidx);

    const int gemmGrid = (NN + 63) / 64;     // 313
    const int edgeGrid = NE / EPB;           // 3125

    for (int hh = 0; hh < HEADS; hh++) {
        mfma_gemm_kernel<0><<<gemmGrid, 256, 0, stream>>>(
            h_bf, WlT + (size_t)hh * OUT * HID, HID, b_l + hh * OUT, xl_bf, NN);
        mfma_gemm_kernel<0><<<gemmGrid, 256, 0, stream>>>(
            h_bf, WrT + (size_t)hh * OUT * HID, HID, b_r + hh * OUT, xr_bf, NN);

        edge_mfma_logits_kernel<<<edgeGrid, 256, 0, stream>>>(
            edge_attr, W_ee, b_ee, WeT + (size_t)hh * OUT * HID,
            b_e + hh * OUT, att + hh * OUT, xl_bf, xr_bf, ei, lbuf4, hh);

        softmax_agg_kernel<<<(NN + 3) / 4, 256, 0, stream>>>(
            lbuf4, rowptr, eidx, ei, xl_bf, agg_bf, hh);

        mfma_gemm_kernel<1><<<gemmGrid, 256, 0, stream>>>(
            agg_bf, Wd1T + hh * OUT, HO, nullptr, hid, NN);
    }

    hid_relu_kernel<<<(NN * HID + 255) / 256, 256, 0, stream>>>(hid, biasH);
    final_kernel<<<(NN * 6 + 255) / 256, 256, 0, stream>>>(hid, W_d2, b_d2, out);
}